// Round 2
// baseline (20282.103 us; speedup 1.0000x reference)
//
#include <hip/hip_runtime.h>
#include <math.h>

#define Bz 32
#define Tz 512
#define Dz 1024
#define Pz 512
#define Ez 256
#define KC 14
#define NHz 4
#define Lz 2
#define FFz 2048
#define TOPKz 7
#define EPSz 1e-5f
#define BT (Bz*Tz)

// ---------------- generic fp32 tiled GEMM: C[M,N] = A[M,K] @ W[K,N] (+bias, epi) --------------
// A row-stride lda, W row-stride ldw, C row-stride ldc. M = gridDim.y*64.
// epi: 0=none, 1=relu, 2=BN(eval)+relu
#define BM 64
#define BN 64
#define BKK 32

__global__ __launch_bounds__(256) void gemm_k(
    const float* __restrict__ A, int lda,
    const float* __restrict__ W, int ldw,
    const float* __restrict__ bias,
    float* __restrict__ C, int ldc,
    int N, int Kd, int epi,
    const float* __restrict__ bng, const float* __restrict__ bnb,
    const float* __restrict__ bnm, const float* __restrict__ bnv)
{
    __shared__ float As[BKK][BM + 4];
    __shared__ float Ws[BKK][BN + 4];
    const int tid = threadIdx.x;
    const int tx = tid & 15, ty = tid >> 4;
    const int row0 = blockIdx.y * BM, col0 = blockIdx.x * BN;
    float acc[4][4] = {};
    for (int k0 = 0; k0 < Kd; k0 += BKK) {
        #pragma unroll
        for (int i = 0; i < 8; i++) {
            int idx = tid + i * 256;
            int mi = idx >> 5, ki = idx & 31;
            As[ki][mi] = A[(size_t)(row0 + mi) * lda + k0 + ki];
        }
        #pragma unroll
        for (int i = 0; i < 8; i++) {
            int idx = tid + i * 256;
            int ki = idx >> 6, ni = idx & 63;
            Ws[ki][ni] = W[(size_t)(k0 + ki) * ldw + col0 + ni];
        }
        __syncthreads();
        #pragma unroll
        for (int kk = 0; kk < BKK; kk++) {
            float a4[4], w4[4];
            #pragma unroll
            for (int i = 0; i < 4; i++) a4[i] = As[kk][ty * 4 + i];
            #pragma unroll
            for (int j = 0; j < 4; j++) w4[j] = Ws[kk][tx * 4 + j];
            #pragma unroll
            for (int i = 0; i < 4; i++)
                #pragma unroll
                for (int j = 0; j < 4; j++)
                    acc[i][j] += a4[i] * w4[j];
        }
        __syncthreads();
    }
    #pragma unroll
    for (int i = 0; i < 4; i++) {
        int r = row0 + ty * 4 + i;
        #pragma unroll
        for (int j = 0; j < 4; j++) {
            int c = col0 + tx * 4 + j;
            float y = acc[i][j] + bias[c];
            if (epi == 2) y = (y - bnm[c]) * rsqrtf(bnv[c] + EPSz) * bng[c] + bnb[c];
            if (epi >= 1) y = fmaxf(y, 0.f);
            C[(size_t)r * ldc + c] = y;
        }
    }
}

// ------------- rowdot: out[row] = dot(in[row,:], w) + b ; mode1: sigmoid->shift count ----------
__global__ __launch_bounds__(256) void rowdot_k(
    const float* __restrict__ in, const float* __restrict__ w,
    const float* __restrict__ bptr, int cols, int mode,
    float* __restrict__ outf, int* __restrict__ outi)
{
    const int row = blockIdx.x, tid = threadIdx.x;
    const float* r = in + (size_t)row * cols;
    float s = 0.f;
    for (int c = tid; c < cols; c += 256) s += r[c] * w[c];
    __shared__ float red[256];
    red[tid] = s; __syncthreads();
    for (int off = 128; off > 0; off >>= 1) {
        if (tid < off) red[tid] += red[tid + off];
        __syncthreads();
    }
    if (tid == 0) {
        float y = red[0] + bptr[0];
        if (mode == 0) outf[row] = y;
        else {
            float sg = 1.f / (1.f + expf(-y));
            outi[row] = (int)(sg * (float)(Dz / 2));  // fold = D/FOLD_DIV
        }
    }
}

// ------------- TSM shift (chunk-local: R rows) -------------------------------------------------
__global__ __launch_bounds__(256) void tsm_k(
    const float* __restrict__ x, const int* __restrict__ sn, float* __restrict__ h)
{
    size_t idx = (size_t)blockIdx.x * 256 + threadIdx.x;   // over R*D
    int c = (int)(idx & (Dz - 1));
    int bt = (int)(idx >> 10);
    int t = bt & (Tz - 1);
    int s = sn[bt];
    float v;
    if (c < s)            v = (t > 0)      ? x[idx - Dz] : 0.f;
    else if (c < 2 * s)   v = (t < Tz - 1) ? x[idx + Dz] : 0.f;
    else                  v = x[idx];
    h[idx] = v;
}

// ------------- self-attention on interleaved qkv[R,3D]; writes o into q-slots in place ---------
// Each block (tq,hh,b) reads its own q slice first, then K/V slices of all rows (never written),
// then overwrites only its own q slice. Race-free.
__global__ __launch_bounds__(256) void attn_k(float* __restrict__ qkv)
{
    const int tq = blockIdx.x, hh = blockIdx.y, b = blockIdx.z;
    const int tid = threadIdx.x;
    __shared__ float qs[256];
    __shared__ float sc[Tz];
    __shared__ float red[256];
    const size_t base = (size_t)b * Tz * 3 * Dz;
    qs[tid] = qkv[base + (size_t)tq * 3 * Dz + hh * 256 + tid];
    __syncthreads();
    for (int t2 = tid; t2 < Tz; t2 += 256) {
        const float* kr = qkv + base + (size_t)t2 * 3 * Dz + Dz + hh * 256;
        float s = 0.f;
        #pragma unroll 8
        for (int d = 0; d < 256; d++) s += qs[d] * kr[d];
        sc[t2] = s * 0.0625f;   // 1/sqrt(256)
    }
    __syncthreads();
    float m = fmaxf(sc[tid], sc[tid + 256]);
    red[tid] = m; __syncthreads();
    for (int off = 128; off > 0; off >>= 1) {
        if (tid < off) red[tid] = fmaxf(red[tid], red[tid + off]);
        __syncthreads();
    }
    float mx = red[0]; __syncthreads();
    float e0 = expf(sc[tid] - mx), e1 = expf(sc[tid + 256] - mx);
    sc[tid] = e0; sc[tid + 256] = e1;
    red[tid] = e0 + e1; __syncthreads();
    for (int off = 128; off > 0; off >>= 1) {
        if (tid < off) red[tid] += red[tid + off];
        __syncthreads();
    }
    float inv = 1.f / red[0];
    float acc = 0.f;
    for (int t2 = 0; t2 < Tz; t2++)
        acc += sc[t2] * qkv[base + (size_t)t2 * 3 * Dz + 2 * Dz + hh * 256 + tid];
    qkv[base + (size_t)tq * 3 * Dz + hh * 256 + tid] = acc * inv;
}

// ------------- h = LN(h + r), r has row-stride ldr ---------------------------------------------
__global__ __launch_bounds__(256) void addln_k(
    float* __restrict__ h, const float* __restrict__ r, int ldr,
    const float* __restrict__ g, const float* __restrict__ b)
{
    const int row = blockIdx.x, tid = threadIdx.x;
    const size_t base = (size_t)row * Dz;
    const size_t baser = (size_t)row * ldr;
    float x[4]; float s = 0.f, sq = 0.f;
    #pragma unroll
    for (int i = 0; i < 4; i++) {
        x[i] = h[base + tid + i * 256] + r[baser + tid + i * 256];
        s += x[i]; sq += x[i] * x[i];
    }
    __shared__ float rs[256], rq[256];
    rs[tid] = s; rq[tid] = sq; __syncthreads();
    for (int off = 128; off > 0; off >>= 1) {
        if (tid < off) { rs[tid] += rs[tid + off]; rq[tid] += rq[tid + off]; }
        __syncthreads();
    }
    float mean = rs[0] * (1.f / Dz);
    float var = rq[0] * (1.f / Dz) - mean * mean;
    float inv = rsqrtf(var + EPSz);
    #pragma unroll
    for (int i = 0; i < 4; i++) {
        int c = tid + i * 256;
        h[base + c] = (x[i] - mean) * inv * g[c] + b[c];
    }
}

// ------------- top-k (7 of 512) per (chunk-local) batch row ------------------------------------
__global__ __launch_bounds__(256) void topk_k(const float* __restrict__ scores, int* __restrict__ idx)
{
    const int b = blockIdx.x, tid = threadIdx.x;
    __shared__ float sv[Tz];
    __shared__ float rv[256]; __shared__ int ri[256];
    sv[tid] = scores[b * Tz + tid];
    sv[tid + 256] = scores[b * Tz + tid + 256];
    __syncthreads();
    for (int it = 0; it < TOPKz; it++) {
        float v0 = sv[tid]; int i0 = tid;
        float v1 = sv[tid + 256];
        if (v1 > v0) { v0 = v1; i0 = tid + 256; }
        rv[tid] = v0; ri[tid] = i0; __syncthreads();
        for (int off = 128; off > 0; off >>= 1) {
            if (tid < off) {
                if (rv[tid + off] > rv[tid] ||
                    (rv[tid + off] == rv[tid] && ri[tid + off] < ri[tid])) {
                    rv[tid] = rv[tid + off]; ri[tid] = ri[tid + off];
                }
            }
            __syncthreads();
        }
        if (tid == 0) { idx[b * TOPKz + it] = ri[0]; sv[ri[0]] = -INFINITY; }
        __syncthreads();
    }
}

// ------------- agg = mean of top-k rows of shared ---------------------------------------------
__global__ __launch_bounds__(256) void agg_k(
    const float* __restrict__ sh, const int* __restrict__ idx, float* __restrict__ agg)
{
    const int b = blockIdx.x, tid = threadIdx.x;
    for (int p = tid; p < Pz; p += 256) {
        float s = 0.f;
        #pragma unroll
        for (int j = 0; j < TOPKz; j++) {
            int t = idx[b * TOPKz + j];
            s += sh[((size_t)b * Tz + t) * Pz + p];
        }
        agg[b * Pz + p] = s * (1.f / TOPKz);
    }
}

// ------------- fused classifier: c1 -> logits -> softmax -> cat_emb -> cross-q -----------------
__global__ __launch_bounds__(256) void cls_k(
    const float* __restrict__ agg,
    const float* __restrict__ cc_w1, const float* __restrict__ cc_b1,
    const float* __restrict__ g2, const float* __restrict__ b2,
    const float* __restrict__ m2, const float* __restrict__ v2,
    const float* __restrict__ cc_w2, const float* __restrict__ cc_b2,
    const float* __restrict__ ce,
    const float* __restrict__ ca_wqkv, const float* __restrict__ ca_bqkv,
    float* __restrict__ logits_out, float* __restrict__ qx)
{
    const int b = blockIdx.x, tid = threadIdx.x;
    __shared__ float ag[Pz], c1s[256], sm[16], cemb[256];
    ag[tid] = agg[b * Pz + tid];
    ag[tid + 256] = agg[b * Pz + tid + 256];
    __syncthreads();
    float s = 0.f;
    for (int p = 0; p < Pz; p++) s += ag[p] * cc_w1[p * 256 + tid];
    s += cc_b1[tid];
    s = (s - m2[tid]) * rsqrtf(v2[tid] + EPSz) * g2[tid] + b2[tid];
    s = fmaxf(s, 0.f);
    c1s[tid] = s;
    __syncthreads();
    if (tid < KC) {
        float l = 0.f;
        for (int e = 0; e < 256; e++) l += c1s[e] * cc_w2[e * KC + tid];
        l += cc_b2[tid];
        sm[tid] = l;
        logits_out[b * KC + tid] = l;
    }
    __syncthreads();
    if (tid == 0) {
        float mx = sm[0];
        for (int k = 1; k < KC; k++) mx = fmaxf(mx, sm[k]);
        float su = 0.f;
        for (int k = 0; k < KC; k++) { sm[k] = expf(sm[k] - mx); su += sm[k]; }
        float inv = 1.f / su;
        for (int k = 0; k < KC; k++) sm[k] *= inv;
    }
    __syncthreads();
    float cesum = 0.f;
    #pragma unroll
    for (int k = 0; k < KC; k++) cesum += sm[k] * ce[k * 256 + tid];
    cemb[tid] = cesum; __syncthreads();
    float q = 0.f;
    for (int i = 0; i < 256; i++) q += cemb[i] * ca_wqkv[i * 768 + tid];
    qx[b * 256 + tid] = q + ca_bqkv[tid];
}

// ------------- cross-attention (Tq=1): per-batch block -----------------------------------------
__global__ __launch_bounds__(256) void xattn_k(
    const float* __restrict__ qx, const float* __restrict__ kc,
    const float* __restrict__ vc, float* __restrict__ ctx)
{
    const int b = blockIdx.x, tid = threadIdx.x;
    __shared__ float q4[256];
    __shared__ float sc[NHz][Tz];
    q4[tid] = qx[b * 256 + tid];
    __syncthreads();
    for (int si = tid; si < NHz * Tz; si += 256) {
        int hh = si >> 9, t = si & (Tz - 1);
        const float* kr = kc + ((size_t)b * Tz + t) * 256 + hh * 64;
        const float* qr = q4 + hh * 64;
        float s = 0.f;
        #pragma unroll 8
        for (int d = 0; d < 64; d++) s += qr[d] * kr[d];
        sc[hh][t] = s * 0.125f;   // 1/sqrt(64)
    }
    __syncthreads();
    const int hh = tid >> 6, lane = tid & 63;
    float mx = -INFINITY;
    for (int t = lane; t < Tz; t += 64) mx = fmaxf(mx, sc[hh][t]);
    for (int off = 32; off > 0; off >>= 1) mx = fmaxf(mx, __shfl_xor(mx, off));
    float su = 0.f;
    for (int t = lane; t < Tz; t += 64) { float e = expf(sc[hh][t] - mx); sc[hh][t] = e; su += e; }
    for (int off = 32; off > 0; off >>= 1) su += __shfl_xor(su, off);
    float inv = 1.f / su;
    __syncthreads();
    float acc = 0.f;
    for (int t = 0; t < Tz; t++) acc += sc[hh][t] * vc[((size_t)b * Tz + t) * 256 + tid];
    ctx[b * 256 + tid] = acc * inv;
}

// ------------- ctx2 = ctx @ ca_wo + ca_bo ------------------------------------------------------
__global__ __launch_bounds__(256) void ctx2_k(
    const float* __restrict__ ctx, const float* __restrict__ ca_wo,
    const float* __restrict__ ca_bo, float* __restrict__ ctx2)
{
    const int b = blockIdx.x, tid = threadIdx.x;
    __shared__ float c[256];
    c[tid] = ctx[b * 256 + tid]; __syncthreads();
    float s = 0.f;
    for (int i = 0; i < 256; i++) s += c[i] * ca_wo[i * 256 + tid];
    ctx2[b * 256 + tid] = s + ca_bo[tid];
}

// ------------- final = proj + ctx2 (broadcast over T) ------------------------------------------
__global__ __launch_bounds__(256) void addctx_k(float* __restrict__ proj, const float* __restrict__ ctx2)
{
    size_t idx = (size_t)blockIdx.x * 256 + threadIdx.x;   // over R*E
    int e = (int)(idx & 255);
    int b = (int)(idx >> 17);                              // T*E = 2^17
    proj[idx] += ctx2[b * 256 + e];
}

// ==============================================================================================
extern "C" void kernel_launch(void* const* d_in, const int* in_sizes, int n_in,
                              void* d_out, int out_size, void* d_ws, size_t ws_size,
                              hipStream_t stream)
{
    const float* x       = (const float*)d_in[0];
    const float* pred_w  = (const float*)d_in[1];
    const float* pred_b  = (const float*)d_in[2];
    const float* t_wqkv  = (const float*)d_in[3];
    const float* t_bqkv  = (const float*)d_in[4];
    const float* t_wo    = (const float*)d_in[5];
    const float* t_bo    = (const float*)d_in[6];
    const float* t_ln1g  = (const float*)d_in[7];
    const float* t_ln1b  = (const float*)d_in[8];
    const float* t_w1    = (const float*)d_in[9];
    const float* t_b1    = (const float*)d_in[10];
    const float* t_w2    = (const float*)d_in[11];
    const float* t_b2    = (const float*)d_in[12];
    const float* t_ln2g  = (const float*)d_in[13];
    const float* t_ln2b  = (const float*)d_in[14];
    const float* sb_w    = (const float*)d_in[15];
    const float* sb_b    = (const float*)d_in[16];
    const float* bn1_g   = (const float*)d_in[17];
    const float* bn1_b   = (const float*)d_in[18];
    const float* bn1_m   = (const float*)d_in[19];
    const float* bn1_v   = (const float*)d_in[20];
    const float* dt_w    = (const float*)d_in[21];
    const float* dt_b    = (const float*)d_in[22];
    const float* cc_w1   = (const float*)d_in[23];
    const float* cc_b1   = (const float*)d_in[24];
    const float* bn2_g   = (const float*)d_in[25];
    const float* bn2_b   = (const float*)d_in[26];
    const float* bn2_m   = (const float*)d_in[27];
    const float* bn2_v   = (const float*)d_in[28];
    const float* cc_w2   = (const float*)d_in[29];
    const float* cc_b2   = (const float*)d_in[30];
    const float* ce      = (const float*)d_in[31];
    const float* kp_w    = (const float*)d_in[32];
    const float* kp_b    = (const float*)d_in[33];
    const float* ca_wqkv = (const float*)d_in[34];
    const float* ca_bqkv = (const float*)d_in[35];
    const float* ca_wo   = (const float*)d_in[36];
    const float* ca_bo   = (const float*)d_in[37];
    const float* fp_w    = (const float*)d_in[38];
    const float* fp_b    = (const float*)d_in[39];
    const float* df_w    = (const float*)d_in[40];
    const float* df_b    = (const float*)d_in[41];

    float* out = (float*)d_out;

    // ---- small (global-sized) buffers at the front of d_ws ----
    float* p = (float*)d_ws;
    int*   sn      = (int*)p;   p += BT;           // shift counts
    float* scores  = p;         p += BT;
    int*   tkidx   = (int*)p;   p += 256;
    float* aggbuf  = p;         p += (size_t)Bz * Pz;
    float* qxbuf   = p;         p += (size_t)Bz * Ez;
    float* ctxbuf  = p;         p += (size_t)Bz * Ez;
    float* ctx2buf = p;         p += (size_t)Bz * Ez;
    float* big     = p;                            // chunk region starts here
    size_t smallF  = (size_t)(big - (float*)d_ws);

    // ---- pick the largest batch-chunk that fits ws_size ----
    // per-chunk big region: h[R*1024] + qkv[R*3072] = R*4096 floats, R = Bc*512
    int Bc = Bz;
    while (Bc > 1) {
        size_t needBytes = (smallF + (size_t)Bc * Tz * 4096) * sizeof(float);
        if (needBytes <= ws_size) break;
        Bc >>= 1;
    }

    for (int b0 = 0; b0 < Bz; b0 += Bc) {
        const int R = Bc * Tz;                 // chunk rows
        float* h   = big;                      // [R,1024]
        float* qkv = big + (size_t)R * Dz;     // [R,3072] interleaved q|k|v
        const float* xc = x + (size_t)b0 * Tz * Dz;
        int* snc = sn + (size_t)b0 * Tz;

        // 1. shift predictor + TSM shift
        rowdot_k<<<R, 256, 0, stream>>>(xc, pred_w, pred_b, Dz, 1, nullptr, snc);
        tsm_k<<<(R * Dz) / 256, 256, 0, stream>>>(xc, snc, h);

        // 2. transformer layers (all big intermediates live inside qkv[R,3072])
        for (int l = 0; l < Lz; l++) {
            // qkv = h @ Wqkv + b
            gemm_k<<<dim3(3 * Dz / BN, R / BM), 256, 0, stream>>>(
                h, Dz, t_wqkv + (size_t)l * Dz * 3 * Dz, 3 * Dz,
                t_bqkv + (size_t)l * 3 * Dz, qkv, 3 * Dz,
                3 * Dz, Dz, 0, nullptr, nullptr, nullptr, nullptr);
            // attention in place: o -> q-slots
            attn_k<<<dim3(Tz, NHz, Bc), 256, 0, stream>>>(qkv);
            // wo: A = o (q-slots, lda=3D), C -> k-slots (ldc=3D, disjoint columns)
            gemm_k<<<dim3(Dz / BN, R / BM), 256, 0, stream>>>(
                qkv, 3 * Dz, t_wo + (size_t)l * Dz * Dz, Dz,
                t_bo + (size_t)l * Dz, qkv + Dz, 3 * Dz,
                Dz, Dz, 0, nullptr, nullptr, nullptr, nullptr);
            addln_k<<<R, 256, 0, stream>>>(h, qkv + Dz, 3 * Dz,
                                           t_ln1g + (size_t)l * Dz, t_ln1b + (size_t)l * Dz);
            // FF1: h @ w1 -> cols 0..2047 of qkv buffer (relu)
            gemm_k<<<dim3(FFz / BN, R / BM), 256, 0, stream>>>(
                h, Dz, t_w1 + (size_t)l * Dz * FFz, FFz,
                t_b1 + (size_t)l * FFz, qkv, 3 * Dz,
                FFz, Dz, 1, nullptr, nullptr, nullptr, nullptr);
            // FF2: reads cols 0..2047, writes cols 2048..3071 (disjoint)
            gemm_k<<<dim3(Dz / BN, R / BM), 256, 0, stream>>>(
                qkv, 3 * Dz, t_w2 + (size_t)l * FFz * Dz, Dz,
                t_b2 + (size_t)l * Dz, qkv + FFz, 3 * Dz,
                Dz, FFz, 0, nullptr, nullptr, nullptr, nullptr);
            addln_k<<<R, 256, 0, stream>>>(h, qkv + FFz, 3 * Dz,
                                           t_ln2g + (size_t)l * Dz, t_ln2b + (size_t)l * Dz);
        }

        // post-transformer tail: sublet the (dead) qkv region
        float* shared = qkv;                          // [R,512]
        float* proj   = qkv + (size_t)R * Pz;         // [R,256]
        float* kbuf   = proj + (size_t)R * Ez;        // [R,256]
        float* vbuf   = kbuf + (size_t)R * Ez;        // [R,256]
        float* fin    = vbuf + (size_t)R * Ez;        // [R,512]  (total R*1792 <= R*3072)

        // 3. shared = relu(BN1(h @ sb_w + sb_b))
        gemm_k<<<dim3(Pz / BN, R / BM), 256, 0, stream>>>(
            h, Dz, sb_w, Pz, sb_b, shared, Pz,
            Pz, Dz, 2, bn1_g, bn1_b, bn1_m, bn1_v);
        // 4. top_scores, top-k, agg
        rowdot_k<<<R, 256, 0, stream>>>(shared, dt_w, dt_b, Pz, 0,
                                        scores + (size_t)b0 * Tz, nullptr);
        topk_k<<<Bc, 256, 0, stream>>>(scores + (size_t)b0 * Tz, tkidx);
        agg_k<<<Bc, 256, 0, stream>>>(shared, tkidx, aggbuf);
        // 5. classifier head -> logits (d_out tail) + cross-attn q
        cls_k<<<Bc, 256, 0, stream>>>(aggbuf, cc_w1, cc_b1, bn2_g, bn2_b, bn2_m, bn2_v,
                                      cc_w2, cc_b2, ce, ca_wqkv, ca_bqkv,
                                      out + BT + (size_t)b0 * KC, qxbuf);
        // 6. proj = shared @ kp_w + kp_b
        gemm_k<<<dim3(Ez / BN, R / BM), 256, 0, stream>>>(
            shared, Pz, kp_w, Ez, kp_b, proj, Ez,
            Ez, Pz, 0, nullptr, nullptr, nullptr, nullptr);
        // 7. cross k, v
        gemm_k<<<dim3(Ez / BN, R / BM), 256, 0, stream>>>(
            proj, Ez, ca_wqkv + Ez, 3 * Ez, ca_bqkv + Ez, kbuf, Ez,
            Ez, Ez, 0, nullptr, nullptr, nullptr, nullptr);
        gemm_k<<<dim3(Ez / BN, R / BM), 256, 0, stream>>>(
            proj, Ez, ca_wqkv + 2 * Ez, 3 * Ez, ca_bqkv + 2 * Ez, vbuf, Ez,
            Ez, Ez, 0, nullptr, nullptr, nullptr, nullptr);
        // 8. cross attention -> ctx ; project -> ctx2 ; final = proj + ctx2
        xattn_k<<<Bc, 256, 0, stream>>>(qxbuf, kbuf, vbuf, ctxbuf);
        ctx2_k<<<Bc, 256, 0, stream>>>(ctxbuf, ca_wo, ca_bo, ctx2buf);
        addctx_k<<<(R * Ez) / 256, 256, 0, stream>>>(proj, ctx2buf);
        // 9. fp_out = final @ fp_w + fp_b   (h is dead -> reuse)
        gemm_k<<<dim3(Dz / BN, R / BM), 256, 0, stream>>>(
            proj, Ez, fp_w, Dz, fp_b, h, Dz,
            Dz, Ez, 0, nullptr, nullptr, nullptr, nullptr);
        // 10. fin_proj = relu(BN1(fp_out @ sb_w + sb_b))
        gemm_k<<<dim3(Pz / BN, R / BM), 256, 0, stream>>>(
            h, Dz, sb_w, Pz, sb_b, fin, Pz,
            Pz, Dz, 2, bn1_g, bn1_b, bn1_m, bn1_v);
        // 11. seg
        rowdot_k<<<R, 256, 0, stream>>>(fin, df_w, df_b, Pz, 0,
                                        out + (size_t)b0 * Tz, nullptr);
    }
}

// Round 3
// 13002.898 us; speedup vs baseline: 1.5598x; 1.5598x over previous
//
#include <hip/hip_runtime.h>
#include <math.h>

#define Bz 32
#define Tz 512
#define Dz 1024
#define Pz 512
#define Ez 256
#define KC 14
#define NHz 4
#define Lz 2
#define FFz 2048
#define TOPKz 7
#define EPSz 1e-5f
#define BT (Bz*Tz)

typedef unsigned short ushort_t;
typedef __attribute__((ext_vector_type(8))) short short8;
typedef __attribute__((ext_vector_type(4))) float f32x4;

__device__ __forceinline__ ushort_t f2bf(float f) {
    union { float f; unsigned int u; } x; x.f = f;
    unsigned int r = x.u + 0x7fffu + ((x.u >> 16) & 1u);   // RNE (finite inputs)
    return (ushort_t)(r >> 16);
}

// ---------------- bf16 MFMA GEMM: C[M,N]fp32 = A[M,K]bf16 @ W^T[N,K]bf16 (+bias, epi) ---------
// 128x128 tile, BK=32, 4 waves, global_load_lds(16B) staging, mfma_f32_16x16x32_bf16.
// epi: 0=none, 1=relu, 2=BN(eval)+relu
__global__ __launch_bounds__(256) void mgemm_k(
    const ushort_t* __restrict__ A, int lda,          // [M][K] bf16 bits, row stride lda
    const ushort_t* __restrict__ Wt,                  // [N][Kd] bf16 bits, packed
    const float* __restrict__ bias,
    float* __restrict__ C, int ldc,
    int Kd, int epi,
    const float* __restrict__ bng, const float* __restrict__ bnb,
    const float* __restrict__ bnm, const float* __restrict__ bnv)
{
    __shared__ __align__(16) ushort_t As[128 * 32];
    __shared__ __align__(16) ushort_t Bs[128 * 32];
    const int tid = threadIdx.x;
    const int lane = tid & 63, wid = tid >> 6;
    const int row0 = blockIdx.y * 128, col0 = blockIdx.x * 128;
    const int wrow = (wid >> 1) * 64, wcol = (wid & 1) * 64;

    const int srow = (lane >> 2);          // 0..15 within 16-row stripe
    const int skoff = (lane & 3) * 8;      // k element offset (16B per lane)

    f32x4 acc[4][4];
    const f32x4 zr = {0.f, 0.f, 0.f, 0.f};
    #pragma unroll
    for (int m = 0; m < 4; m++)
        #pragma unroll
        for (int n = 0; n < 4; n++) acc[m][n] = zr;

    for (int k0 = 0; k0 < Kd; k0 += 32) {
        #pragma unroll
        for (int j = 0; j < 2; j++) {
            const int r = wid * 32 + j * 16;
            const ushort_t* ga = A + (size_t)(row0 + r + srow) * lda + k0 + skoff;
            __builtin_amdgcn_global_load_lds(
                (const __attribute__((address_space(1))) unsigned int*)ga,
                (__attribute__((address_space(3))) unsigned int*)(As + r * 32), 16, 0, 0);
            const ushort_t* gb = Wt + (size_t)(col0 + r + srow) * Kd + k0 + skoff;
            __builtin_amdgcn_global_load_lds(
                (const __attribute__((address_space(1))) unsigned int*)gb,
                (__attribute__((address_space(3))) unsigned int*)(Bs + r * 32), 16, 0, 0);
        }
        __syncthreads();
        short8 af[4], bf[4];
        #pragma unroll
        for (int m = 0; m < 4; m++)
            af[m] = *(const short8*)(As + (wrow + m * 16 + (lane & 15)) * 32 + (lane >> 4) * 8);
        #pragma unroll
        for (int n = 0; n < 4; n++)
            bf[n] = *(const short8*)(Bs + (wcol + n * 16 + (lane & 15)) * 32 + (lane >> 4) * 8);
        #pragma unroll
        for (int m = 0; m < 4; m++)
            #pragma unroll
            for (int n = 0; n < 4; n++)
                acc[m][n] = __builtin_amdgcn_mfma_f32_16x16x32_bf16(af[m], bf[n], acc[m][n], 0, 0, 0);
        __syncthreads();
    }

    #pragma unroll
    for (int n = 0; n < 4; n++) {
        const int ccol = col0 + wcol + n * 16 + (lane & 15);
        const float bb = bias[ccol];
        float bsc = 1.f, bsh = 0.f;
        if (epi == 2) {
            bsc = rsqrtf(bnv[ccol] + EPSz) * bng[ccol];
            bsh = bnb[ccol] - bnm[ccol] * bsc;
        }
        #pragma unroll
        for (int m = 0; m < 4; m++) {
            #pragma unroll
            for (int r = 0; r < 4; r++) {
                const int crow = row0 + wrow + m * 16 + (lane >> 4) * 4 + r;
                float y = acc[m][n][r] + bb;
                if (epi == 2) y = y * bsc + bsh;
                if (epi >= 1) y = fmaxf(y, 0.f);
                C[(size_t)crow * ldc + ccol] = y;
            }
        }
    }
}

// ------------- cast fp32 (strided rows) -> packed bf16; cols is a power of two -----------------
__global__ __launch_bounds__(256) void cast_k(
    const float* __restrict__ in, int lda, ushort_t* __restrict__ outp, int logc)
{
    const size_t i4 = ((size_t)blockIdx.x * 256 + threadIdx.x) * 4;
    const size_t r = i4 >> logc;
    const int c = (int)(i4 & (((size_t)1 << logc) - 1));
    const float4 v = *(const float4*)(in + r * lda + c);
    union { ushort_t h[4]; uint2 u; } pk;
    pk.h[0] = f2bf(v.x); pk.h[1] = f2bf(v.y); pk.h[2] = f2bf(v.z); pk.h[3] = f2bf(v.w);
    *(uint2*)(outp + i4) = pk.u;
}

// ------------- transpose+cast weight: src fp32 [Kd][N] (row stride ld) -> dst bf16 [N][Kd] -----
__global__ __launch_bounds__(256) void wt_k(
    const float* __restrict__ src, int ld, int Kd, ushort_t* __restrict__ dst)
{
    __shared__ float t[32][33];
    const int tx = threadIdx.x & 31, ty = threadIdx.x >> 5;   // ty 0..7
    const int gx = blockIdx.x * 32;   // N dir
    const int gy = blockIdx.y * 32;   // K dir
    #pragma unroll
    for (int i = 0; i < 4; i++) {
        const int row = ty + i * 8;
        t[row][tx] = src[(size_t)(gy + row) * ld + gx + tx];
    }
    __syncthreads();
    #pragma unroll
    for (int i = 0; i < 4; i++) {
        const int nr = ty + i * 8;
        dst[(size_t)(gx + nr) * Kd + gy + tx] = f2bf(t[tx][nr]);
    }
}

// ------------- rowdot: out[row] = dot(in[row,:], w) + b ; mode1: sigmoid->shift count ----------
__global__ __launch_bounds__(256) void rowdot_k(
    const float* __restrict__ in, const float* __restrict__ w,
    const float* __restrict__ bptr, int cols, int mode,
    float* __restrict__ outf, int* __restrict__ outi)
{
    const int row = blockIdx.x, tid = threadIdx.x;
    const float* r = in + (size_t)row * cols;
    float s = 0.f;
    for (int c = tid; c < cols; c += 256) s += r[c] * w[c];
    __shared__ float red[256];
    red[tid] = s; __syncthreads();
    for (int off = 128; off > 0; off >>= 1) {
        if (tid < off) red[tid] += red[tid + off];
        __syncthreads();
    }
    if (tid == 0) {
        float y = red[0] + bptr[0];
        if (mode == 0) outf[row] = y;
        else {
            float sg = 1.f / (1.f + expf(-y));
            outi[row] = (int)(sg * (float)(Dz / 2));  // fold = D/FOLD_DIV
        }
    }
}

// ------------- TSM shift (chunk-local: R rows) -------------------------------------------------
__global__ __launch_bounds__(256) void tsm_k(
    const float* __restrict__ x, const int* __restrict__ sn, float* __restrict__ h)
{
    size_t idx = (size_t)blockIdx.x * 256 + threadIdx.x;   // over R*D
    int c = (int)(idx & (Dz - 1));
    int bt = (int)(idx >> 10);
    int t = bt & (Tz - 1);
    int s = sn[bt];
    float v;
    if (c < s)            v = (t > 0)      ? x[idx - Dz] : 0.f;
    else if (c < 2 * s)   v = (t < Tz - 1) ? x[idx + Dz] : 0.f;
    else                  v = x[idx];
    h[idx] = v;
}

// ------------- self-attention on interleaved qkv[R,3D]; writes o into q-slots in place ---------
__global__ __launch_bounds__(256) void attn_k(float* __restrict__ qkv)
{
    const int tq = blockIdx.x, hh = blockIdx.y, b = blockIdx.z;
    const int tid = threadIdx.x;
    __shared__ float qs[256];
    __shared__ float sc[Tz];
    __shared__ float red[256];
    const size_t base = (size_t)b * Tz * 3 * Dz;
    qs[tid] = qkv[base + (size_t)tq * 3 * Dz + hh * 256 + tid];
    __syncthreads();
    for (int t2 = tid; t2 < Tz; t2 += 256) {
        const float* kr = qkv + base + (size_t)t2 * 3 * Dz + Dz + hh * 256;
        float s = 0.f;
        #pragma unroll 8
        for (int d = 0; d < 256; d++) s += qs[d] * kr[d];
        sc[t2] = s * 0.0625f;   // 1/sqrt(256)
    }
    __syncthreads();
    float m = fmaxf(sc[tid], sc[tid + 256]);
    red[tid] = m; __syncthreads();
    for (int off = 128; off > 0; off >>= 1) {
        if (tid < off) red[tid] = fmaxf(red[tid], red[tid + off]);
        __syncthreads();
    }
    float mx = red[0]; __syncthreads();
    float e0 = expf(sc[tid] - mx), e1 = expf(sc[tid + 256] - mx);
    sc[tid] = e0; sc[tid + 256] = e1;
    red[tid] = e0 + e1; __syncthreads();
    for (int off = 128; off > 0; off >>= 1) {
        if (tid < off) red[tid] += red[tid + off];
        __syncthreads();
    }
    float inv = 1.f / red[0];
    float acc = 0.f;
    for (int t2 = 0; t2 < Tz; t2++)
        acc += sc[t2] * qkv[base + (size_t)t2 * 3 * Dz + 2 * Dz + hh * 256 + tid];
    qkv[base + (size_t)tq * 3 * Dz + hh * 256 + tid] = acc * inv;
}

// ------------- h = LN(h + r), r has row-stride ldr ---------------------------------------------
__global__ __launch_bounds__(256) void addln_k(
    float* __restrict__ h, const float* __restrict__ r, int ldr,
    const float* __restrict__ g, const float* __restrict__ b)
{
    const int row = blockIdx.x, tid = threadIdx.x;
    const size_t base = (size_t)row * Dz;
    const size_t baser = (size_t)row * ldr;
    float x[4]; float s = 0.f, sq = 0.f;
    #pragma unroll
    for (int i = 0; i < 4; i++) {
        x[i] = h[base + tid + i * 256] + r[baser + tid + i * 256];
        s += x[i]; sq += x[i] * x[i];
    }
    __shared__ float rs[256], rq[256];
    rs[tid] = s; rq[tid] = sq; __syncthreads();
    for (int off = 128; off > 0; off >>= 1) {
        if (tid < off) { rs[tid] += rs[tid + off]; rq[tid] += rq[tid + off]; }
        __syncthreads();
    }
    float mean = rs[0] * (1.f / Dz);
    float var = rq[0] * (1.f / Dz) - mean * mean;
    float inv = rsqrtf(var + EPSz);
    #pragma unroll
    for (int i = 0; i < 4; i++) {
        int c = tid + i * 256;
        h[base + c] = (x[i] - mean) * inv * g[c] + b[c];
    }
}

// ------------- top-k (7 of 512) per (chunk-local) batch row ------------------------------------
__global__ __launch_bounds__(256) void topk_k(const float* __restrict__ scores, int* __restrict__ idx)
{
    const int b = blockIdx.x, tid = threadIdx.x;
    __shared__ float sv[Tz];
    __shared__ float rv[256]; __shared__ int ri[256];
    sv[tid] = scores[b * Tz + tid];
    sv[tid + 256] = scores[b * Tz + tid + 256];
    __syncthreads();
    for (int it = 0; it < TOPKz; it++) {
        float v0 = sv[tid]; int i0 = tid;
        float v1 = sv[tid + 256];
        if (v1 > v0) { v0 = v1; i0 = tid + 256; }
        rv[tid] = v0; ri[tid] = i0; __syncthreads();
        for (int off = 128; off > 0; off >>= 1) {
            if (tid < off) {
                if (rv[tid + off] > rv[tid] ||
                    (rv[tid + off] == rv[tid] && ri[tid + off] < ri[tid])) {
                    rv[tid] = rv[tid + off]; ri[tid] = ri[tid + off];
                }
            }
            __syncthreads();
        }
        if (tid == 0) { idx[b * TOPKz + it] = ri[0]; sv[ri[0]] = -INFINITY; }
        __syncthreads();
    }
}

// ------------- agg = mean of top-k rows of shared ---------------------------------------------
__global__ __launch_bounds__(256) void agg_k(
    const float* __restrict__ sh, const int* __restrict__ idx, float* __restrict__ agg)
{
    const int b = blockIdx.x, tid = threadIdx.x;
    for (int p = tid; p < Pz; p += 256) {
        float s = 0.f;
        #pragma unroll
        for (int j = 0; j < TOPKz; j++) {
            int t = idx[b * TOPKz + j];
            s += sh[((size_t)b * Tz + t) * Pz + p];
        }
        agg[b * Pz + p] = s * (1.f / TOPKz);
    }
}

// ------------- fused classifier: c1 -> logits -> softmax -> cat_emb -> cross-q -----------------
__global__ __launch_bounds__(256) void cls_k(
    const float* __restrict__ agg,
    const float* __restrict__ cc_w1, const float* __restrict__ cc_b1,
    const float* __restrict__ g2, const float* __restrict__ b2,
    const float* __restrict__ m2, const float* __restrict__ v2,
    const float* __restrict__ cc_w2, const float* __restrict__ cc_b2,
    const float* __restrict__ ce,
    const float* __restrict__ ca_wqkv, const float* __restrict__ ca_bqkv,
    float* __restrict__ logits_out, float* __restrict__ qx)
{
    const int b = blockIdx.x, tid = threadIdx.x;
    __shared__ float ag[Pz], c1s[256], sm[16], cemb[256];
    ag[tid] = agg[b * Pz + tid];
    ag[tid + 256] = agg[b * Pz + tid + 256];
    __syncthreads();
    float s = 0.f;
    for (int p = 0; p < Pz; p++) s += ag[p] * cc_w1[p * 256 + tid];
    s += cc_b1[tid];
    s = (s - m2[tid]) * rsqrtf(v2[tid] + EPSz) * g2[tid] + b2[tid];
    s = fmaxf(s, 0.f);
    c1s[tid] = s;
    __syncthreads();
    if (tid < KC) {
        float l = 0.f;
        for (int e = 0; e < 256; e++) l += c1s[e] * cc_w2[e * KC + tid];
        l += cc_b2[tid];
        sm[tid] = l;
        logits_out[b * KC + tid] = l;
    }
    __syncthreads();
    if (tid == 0) {
        float mx = sm[0];
        for (int k = 1; k < KC; k++) mx = fmaxf(mx, sm[k]);
        float su = 0.f;
        for (int k = 0; k < KC; k++) { sm[k] = expf(sm[k] - mx); su += sm[k]; }
        float inv = 1.f / su;
        for (int k = 0; k < KC; k++) sm[k] *= inv;
    }
    __syncthreads();
    float cesum = 0.f;
    #pragma unroll
    for (int k = 0; k < KC; k++) cesum += sm[k] * ce[k * 256 + tid];
    cemb[tid] = cesum; __syncthreads();
    float q = 0.f;
    for (int i = 0; i < 256; i++) q += cemb[i] * ca_wqkv[i * 768 + tid];
    qx[b * 256 + tid] = q + ca_bqkv[tid];
}

// ------------- cross-attention (Tq=1): per-batch block -----------------------------------------
__global__ __launch_bounds__(256) void xattn_k(
    const float* __restrict__ qx, const float* __restrict__ kc,
    const float* __restrict__ vc, float* __restrict__ ctx)
{
    const int b = blockIdx.x, tid = threadIdx.x;
    __shared__ float q4[256];
    __shared__ float sc[NHz][Tz];
    q4[tid] = qx[b * 256 + tid];
    __syncthreads();
    for (int si = tid; si < NHz * Tz; si += 256) {
        int hh = si >> 9, t = si & (Tz - 1);
        const float* kr = kc + ((size_t)b * Tz + t) * 256 + hh * 64;
        const float* qr = q4 + hh * 64;
        float s = 0.f;
        #pragma unroll 8
        for (int d = 0; d < 64; d++) s += qr[d] * kr[d];
        sc[hh][t] = s * 0.125f;   // 1/sqrt(64)
    }
    __syncthreads();
    const int hh = tid >> 6, lane = tid & 63;
    float mx = -INFINITY;
    for (int t = lane; t < Tz; t += 64) mx = fmaxf(mx, sc[hh][t]);
    for (int off = 32; off > 0; off >>= 1) mx = fmaxf(mx, __shfl_xor(mx, off));
    float su = 0.f;
    for (int t = lane; t < Tz; t += 64) { float e = expf(sc[hh][t] - mx); sc[hh][t] = e; su += e; }
    for (int off = 32; off > 0; off >>= 1) su += __shfl_xor(su, off);
    float inv = 1.f / su;
    __syncthreads();
    float acc = 0.f;
    for (int t = 0; t < Tz; t++) acc += sc[hh][t] * vc[((size_t)b * Tz + t) * 256 + tid];
    ctx[b * 256 + tid] = acc * inv;
}

// ------------- ctx2 = ctx @ ca_wo + ca_bo ------------------------------------------------------
__global__ __launch_bounds__(256) void ctx2_k(
    const float* __restrict__ ctx, const float* __restrict__ ca_wo,
    const float* __restrict__ ca_bo, float* __restrict__ ctx2)
{
    const int b = blockIdx.x, tid = threadIdx.x;
    __shared__ float c[256];
    c[tid] = ctx[b * 256 + tid]; __syncthreads();
    float s = 0.f;
    for (int i = 0; i < 256; i++) s += c[i] * ca_wo[i * 256 + tid];
    ctx2[b * 256 + tid] = s + ca_bo[tid];
}

// ------------- final = proj + ctx2 (broadcast over T) ------------------------------------------
__global__ __launch_bounds__(256) void addctx_k(float* __restrict__ proj, const float* __restrict__ ctx2)
{
    size_t idx = (size_t)blockIdx.x * 256 + threadIdx.x;   // over R*E
    int e = (int)(idx & 255);
    int b = (int)(idx >> 17);                              // T*E = 2^17
    proj[idx] += ctx2[b * 256 + e];
}

// ==============================================================================================
extern "C" void kernel_launch(void* const* d_in, const int* in_sizes, int n_in,
                              void* d_out, int out_size, void* d_ws, size_t ws_size,
                              hipStream_t stream)
{
    const float* x       = (const float*)d_in[0];
    const float* pred_w  = (const float*)d_in[1];
    const float* pred_b  = (const float*)d_in[2];
    const float* t_wqkv  = (const float*)d_in[3];
    const float* t_bqkv  = (const float*)d_in[4];
    const float* t_wo    = (const float*)d_in[5];
    const float* t_bo    = (const float*)d_in[6];
    const float* t_ln1g  = (const float*)d_in[7];
    const float* t_ln1b  = (const float*)d_in[8];
    const float* t_w1    = (const float*)d_in[9];
    const float* t_b1    = (const float*)d_in[10];
    const float* t_w2    = (const float*)d_in[11];
    const float* t_b2    = (const float*)d_in[12];
    const float* t_ln2g  = (const float*)d_in[13];
    const float* t_ln2b  = (const float*)d_in[14];
    const float* sb_w    = (const float*)d_in[15];
    const float* sb_b    = (const float*)d_in[16];
    const float* bn1_g   = (const float*)d_in[17];
    const float* bn1_b   = (const float*)d_in[18];
    const float* bn1_m   = (const float*)d_in[19];
    const float* bn1_v   = (const float*)d_in[20];
    const float* dt_w    = (const float*)d_in[21];
    const float* dt_b    = (const float*)d_in[22];
    const float* cc_w1   = (const float*)d_in[23];
    const float* cc_b1   = (const float*)d_in[24];
    const float* bn2_g   = (const float*)d_in[25];
    const float* bn2_b   = (const float*)d_in[26];
    const float* bn2_m   = (const float*)d_in[27];
    const float* bn2_v   = (const float*)d_in[28];
    const float* cc_w2   = (const float*)d_in[29];
    const float* cc_b2   = (const float*)d_in[30];
    const float* ce      = (const float*)d_in[31];
    const float* kp_w    = (const float*)d_in[32];
    const float* kp_b    = (const float*)d_in[33];
    const float* ca_wqkv = (const float*)d_in[34];
    const float* ca_bqkv = (const float*)d_in[35];
    const float* ca_wo   = (const float*)d_in[36];
    const float* ca_bo   = (const float*)d_in[37];
    const float* fp_w    = (const float*)d_in[38];
    const float* fp_b    = (const float*)d_in[39];
    const float* df_w    = (const float*)d_in[40];
    const float* df_b    = (const float*)d_in[41];

    float* out = (float*)d_out;

    // ---- workspace carving (256B-aligned regions) ----
    char* wp = (char*)d_ws;
    auto alloc = [&](size_t bytes) -> char* {
        char* r = wp; wp += (bytes + 255) & ~(size_t)255; return r;
    };
    int*   sn      = (int*)alloc(BT * 4);
    float* scores  = (float*)alloc(BT * 4);
    int*   tkidx   = (int*)alloc(256 * 4);
    float* aggbuf  = (float*)alloc((size_t)Bz * Pz * 4);
    float* qxbuf   = (float*)alloc((size_t)Bz * Ez * 4);
    float* ctxbuf  = (float*)alloc((size_t)Bz * Ez * 4);
    float* ctx2buf = (float*)alloc((size_t)Bz * Ez * 4);

    // transposed bf16 weights
    const size_t WT_TOTAL = 2*(size_t)3072*1024 + 2*(size_t)1024*1024 + 2*(size_t)2048*1024
                          + 2*(size_t)1024*2048 + (size_t)512*1024 + (size_t)256*512
                          + 2*(size_t)256*256 + (size_t)1024*256;
    ushort_t* wtb = (ushort_t*)alloc(WT_TOTAL * 2);
    size_t woff = 0;
    auto nxt = [&](size_t n) -> ushort_t* { ushort_t* r = wtb + woff; woff += n; return r; };
    ushort_t* qkvT[2] = { nxt((size_t)3072*1024), nxt((size_t)3072*1024) };
    ushort_t* woT[2]  = { nxt((size_t)1024*1024), nxt((size_t)1024*1024) };
    ushort_t* w1T[2]  = { nxt((size_t)2048*1024), nxt((size_t)2048*1024) };
    ushort_t* w2T[2]  = { nxt((size_t)1024*2048), nxt((size_t)1024*2048) };
    ushort_t* sbT  = nxt((size_t)512*1024);
    ushort_t* kpT  = nxt((size_t)256*512);
    ushort_t* cakT = nxt((size_t)256*256);
    ushort_t* cavT = nxt((size_t)256*256);
    ushort_t* fpT  = nxt((size_t)1024*256);

    // ---- chunk sizing: per row abuf(2048 bf16)=4KB + h(1024 f32)=4KB + qkv(3072 f32)=12KB ----
    size_t fixedB = (size_t)(wp - (char*)d_ws);
    int Bc = Bz;
    while (Bc > 1 && fixedB + (size_t)Bc * Tz * 20480 + 1048576 > ws_size) Bc >>= 1;
    ushort_t* abuf = (ushort_t*)alloc((size_t)Bc * Tz * 2048 * 2);
    float*    h    = (float*)alloc((size_t)Bc * Tz * 1024 * 4);
    float*    qkv  = (float*)alloc((size_t)Bc * Tz * 3072 * 4);

    // ---- one-time weight transpose+cast (13 launches) ----
    for (int l = 0; l < Lz; l++) {
        wt_k<<<dim3(3072/32, 1024/32), 256, 0, stream>>>(t_wqkv + (size_t)l*1024*3072, 3072, 1024, qkvT[l]);
        wt_k<<<dim3(1024/32, 1024/32), 256, 0, stream>>>(t_wo   + (size_t)l*1024*1024, 1024, 1024, woT[l]);
        wt_k<<<dim3(2048/32, 1024/32), 256, 0, stream>>>(t_w1   + (size_t)l*1024*2048, 2048, 1024, w1T[l]);
        wt_k<<<dim3(1024/32, 2048/32), 256, 0, stream>>>(t_w2   + (size_t)l*2048*1024, 1024, 2048, w2T[l]);
    }
    wt_k<<<dim3(512/32, 1024/32), 256, 0, stream>>>(sb_w, 512, 1024, sbT);
    wt_k<<<dim3(256/32,  512/32), 256, 0, stream>>>(kp_w, 256, 512, kpT);
    wt_k<<<dim3(256/32,  256/32), 256, 0, stream>>>(ca_wqkv + Ez,     768, 256, cakT);
    wt_k<<<dim3(256/32,  256/32), 256, 0, stream>>>(ca_wqkv + 2*Ez,   768, 256, cavT);
    wt_k<<<dim3(1024/32, 256/32), 256, 0, stream>>>(fp_w, 1024, 256, fpT);

    for (int b0 = 0; b0 < Bz; b0 += Bc) {
        const int R = Bc * Tz;
        const float* xc = x + (size_t)b0 * Tz * Dz;
        int* snc = sn + (size_t)b0 * Tz;

        auto castA = [&](const float* src, int lda, int cols, int logc) {
            cast_k<<<(int)(((size_t)R * cols) / 1024), 256, 0, stream>>>(src, lda, abuf, logc);
        };
        auto MG = [&](int aldacols, const ushort_t* Wt, const float* bias,
                      float* C, int ldc, int N, int Kd, int epi,
                      const float* g = nullptr, const float* bb = nullptr,
                      const float* m = nullptr, const float* v = nullptr) {
            mgemm_k<<<dim3(N/128, R/128), 256, 0, stream>>>(
                abuf, aldacols, Wt, bias, C, ldc, Kd, epi, g, bb, m, v);
        };

        // 1. shift predictor + TSM shift
        rowdot_k<<<R, 256, 0, stream>>>(xc, pred_w, pred_b, Dz, 1, nullptr, snc);
        tsm_k<<<(R * Dz) / 256, 256, 0, stream>>>(xc, snc, h);

        // 2. transformer layers
        for (int l = 0; l < Lz; l++) {
            castA(h, Dz, 1024, 10);
            MG(1024, qkvT[l], t_bqkv + (size_t)l*3072, qkv, 3072, 3072, 1024, 0);
            attn_k<<<dim3(Tz, NHz, Bc), 256, 0, stream>>>(qkv);
            castA(qkv, 3072, 1024, 10);           // attn-out in q-slots
            MG(1024, woT[l], t_bo + (size_t)l*1024, qkv + Dz, 3072, 1024, 1024, 0);
            addln_k<<<R, 256, 0, stream>>>(h, qkv + Dz, 3072,
                                           t_ln1g + (size_t)l*Dz, t_ln1b + (size_t)l*Dz);
            castA(h, Dz, 1024, 10);
            MG(1024, w1T[l], t_b1 + (size_t)l*FFz, qkv, 3072, 2048, 1024, 1);
            castA(qkv, 3072, 2048, 11);           // ff mid (cols 0..2047)
            MG(2048, w2T[l], t_b2 + (size_t)l*Dz, qkv + FFz, 3072, 1024, 2048, 0);
            addln_k<<<R, 256, 0, stream>>>(h, qkv + FFz, 3072,
                                           t_ln2g + (size_t)l*Dz, t_ln2b + (size_t)l*Dz);
        }

        // tail buffers sublet the dead qkv region
        float* shared = qkv;                      // [R,512]
        float* proj   = qkv + (size_t)R * Pz;     // [R,256]
        float* kbuf   = proj + (size_t)R * Ez;    // [R,256]
        float* vbuf   = kbuf + (size_t)R * Ez;    // [R,256]
        float* fin    = vbuf + (size_t)R * Ez;    // [R,512]

        // 3. shared = relu(BN1(h @ sb_w + sb_b))
        castA(h, Dz, 1024, 10);
        MG(1024, sbT, sb_b, shared, Pz, 512, 1024, 2, bn1_g, bn1_b, bn1_m, bn1_v);
        // 4. top_scores, top-k, agg
        rowdot_k<<<R, 256, 0, stream>>>(shared, dt_w, dt_b, Pz, 0,
                                        scores + (size_t)b0 * Tz, nullptr);
        topk_k<<<Bc, 256, 0, stream>>>(scores + (size_t)b0 * Tz, tkidx);
        agg_k<<<Bc, 256, 0, stream>>>(shared, tkidx, aggbuf);
        // 5. classifier head -> logits (d_out tail) + cross-attn q
        cls_k<<<Bc, 256, 0, stream>>>(aggbuf, cc_w1, cc_b1, bn2_g, bn2_b, bn2_m, bn2_v,
                                      cc_w2, cc_b2, ce, ca_wqkv, ca_bqkv,
                                      out + BT + (size_t)b0 * KC, qxbuf);
        // 6. proj = shared @ kp_w + kp_b
        castA(shared, Pz, 512, 9);
        MG(512, kpT, kp_b, proj, Ez, 256, 512, 0);
        // 7. cross k, v (one cast of proj feeds both)
        castA(proj, Ez, 256, 8);
        MG(256, cakT, ca_bqkv + Ez,   kbuf, Ez, 256, 256, 0);
        MG(256, cavT, ca_bqkv + 2*Ez, vbuf, Ez, 256, 256, 0);
        // 8. cross attention -> ctx ; project -> ctx2 ; final = proj + ctx2
        xattn_k<<<Bc, 256, 0, stream>>>(qxbuf, kbuf, vbuf, ctxbuf);
        ctx2_k<<<Bc, 256, 0, stream>>>(ctxbuf, ca_wo, ca_bo, ctx2buf);
        addctx_k<<<(R * Ez) / 256, 256, 0, stream>>>(proj, ctx2buf);
        // 9. fp_out = final @ fp_w + fp_b (h is dead -> reuse)
        castA(proj, Ez, 256, 8);
        MG(256, fpT, fp_b, h, Dz, 1024, 256, 0);
        // 10. fin_proj = relu(BN1(fp_out @ sb_w + sb_b))
        castA(h, Dz, 1024, 10);
        MG(1024, sbT, sb_b, fin, Pz, 512, 1024, 2, bn1_g, bn1_b, bn1_m, bn1_v);
        // 11. seg
        rowdot_k<<<R, 256, 0, stream>>>(fin, df_w, df_b, Pz, 0,
                                        out + (size_t)b0 * Tz, nullptr);
    }
}

// Round 4
// 3035.586 us; speedup vs baseline: 6.6814x; 4.2835x over previous
//
#include <hip/hip_runtime.h>
#include <math.h>

#define Bz 32
#define Tz 512
#define Dz 1024
#define Pz 512
#define Ez 256
#define KC 14
#define NHz 4
#define Lz 2
#define FFz 2048
#define TOPKz 7
#define EPSz 1e-5f
#define BT (Bz*Tz)

typedef unsigned short ushort_t;
typedef __attribute__((ext_vector_type(8))) short short8;
typedef __attribute__((ext_vector_type(4))) float f32x4;

__device__ __forceinline__ ushort_t f2bf(float f) {
    union { float f; unsigned int u; } x; x.f = f;
    unsigned int r = x.u + 0x7fffu + ((x.u >> 16) & 1u);   // RNE (finite inputs)
    return (ushort_t)(r >> 16);
}

// ---------------- bf16 MFMA GEMM: C[M,N]fp32 = A[M,K]bf16 @ W^T[N,K]bf16 (+bias, epi) ---------
// 128x128 tile, BK=32, 4 waves, global_load_lds(16B) staging, mfma_f32_16x16x32_bf16.
// epi: 0=none, 1=relu, 2=BN(eval)+relu
__global__ __launch_bounds__(256) void mgemm_k(
    const ushort_t* __restrict__ A, int lda,          // [M][K] bf16 bits, row stride lda
    const ushort_t* __restrict__ Wt,                  // [N][Kd] bf16 bits, packed
    const float* __restrict__ bias,
    float* __restrict__ C, int ldc,
    int Kd, int epi,
    const float* __restrict__ bng, const float* __restrict__ bnb,
    const float* __restrict__ bnm, const float* __restrict__ bnv)
{
    __shared__ __align__(16) ushort_t As[128 * 32];
    __shared__ __align__(16) ushort_t Bs[128 * 32];
    const int tid = threadIdx.x;
    const int lane = tid & 63, wid = tid >> 6;
    const int row0 = blockIdx.y * 128, col0 = blockIdx.x * 128;
    const int wrow = (wid >> 1) * 64, wcol = (wid & 1) * 64;

    const int srow = (lane >> 2);
    const int skoff = (lane & 3) * 8;

    f32x4 acc[4][4];
    const f32x4 zr = {0.f, 0.f, 0.f, 0.f};
    #pragma unroll
    for (int m = 0; m < 4; m++)
        #pragma unroll
        for (int n = 0; n < 4; n++) acc[m][n] = zr;

    for (int k0 = 0; k0 < Kd; k0 += 32) {
        #pragma unroll
        for (int j = 0; j < 2; j++) {
            const int r = wid * 32 + j * 16;
            const ushort_t* ga = A + (size_t)(row0 + r + srow) * lda + k0 + skoff;
            __builtin_amdgcn_global_load_lds(
                (const __attribute__((address_space(1))) unsigned int*)ga,
                (__attribute__((address_space(3))) unsigned int*)(As + r * 32), 16, 0, 0);
            const ushort_t* gb = Wt + (size_t)(col0 + r + srow) * Kd + k0 + skoff;
            __builtin_amdgcn_global_load_lds(
                (const __attribute__((address_space(1))) unsigned int*)gb,
                (__attribute__((address_space(3))) unsigned int*)(Bs + r * 32), 16, 0, 0);
        }
        __syncthreads();
        short8 af[4], bf[4];
        #pragma unroll
        for (int m = 0; m < 4; m++)
            af[m] = *(const short8*)(As + (wrow + m * 16 + (lane & 15)) * 32 + (lane >> 4) * 8);
        #pragma unroll
        for (int n = 0; n < 4; n++)
            bf[n] = *(const short8*)(Bs + (wcol + n * 16 + (lane & 15)) * 32 + (lane >> 4) * 8);
        #pragma unroll
        for (int m = 0; m < 4; m++)
            #pragma unroll
            for (int n = 0; n < 4; n++)
                acc[m][n] = __builtin_amdgcn_mfma_f32_16x16x32_bf16(af[m], bf[n], acc[m][n], 0, 0, 0);
        __syncthreads();
    }

    #pragma unroll
    for (int n = 0; n < 4; n++) {
        const int ccol = col0 + wcol + n * 16 + (lane & 15);
        const float bb = bias[ccol];
        float bsc = 1.f, bsh = 0.f;
        if (epi == 2) {
            bsc = rsqrtf(bnv[ccol] + EPSz) * bng[ccol];
            bsh = bnb[ccol] - bnm[ccol] * bsc;
        }
        #pragma unroll
        for (int m = 0; m < 4; m++) {
            #pragma unroll
            for (int r = 0; r < 4; r++) {
                const int crow = row0 + wrow + m * 16 + (lane >> 4) * 4 + r;
                float y = acc[m][n][r] + bb;
                if (epi == 2) y = y * bsc + bsh;
                if (epi >= 1) y = fmaxf(y, 0.f);
                C[(size_t)crow * ldc + ccol] = y;
            }
        }
    }
}

// ---------------- batched bf16 MFMA GEMM over z=(batch,head): no bias/epi ----------------------
// per z: A = A0 + (z>>2)*Abz + (z&3)*Ahz  (elems), same for W, C. W row-stride ldw.
__global__ __launch_bounds__(256) void bgemm_k(
    const ushort_t* __restrict__ A0, int lda, size_t Abz, int Ahz,
    const ushort_t* __restrict__ W0, int ldw, size_t Wbz, int Whz,
    float* __restrict__ C0, int ldc, size_t Cbz, int Chz, int Kd)
{
    const int z = blockIdx.z, bl = z >> 2, hh = z & 3;
    const ushort_t* A = A0 + (size_t)bl * Abz + (size_t)hh * Ahz;
    const ushort_t* W = W0 + (size_t)bl * Wbz + (size_t)hh * Whz;
    float* C = C0 + (size_t)bl * Cbz + (size_t)hh * Chz;

    __shared__ __align__(16) ushort_t As[128 * 32];
    __shared__ __align__(16) ushort_t Bs[128 * 32];
    const int tid = threadIdx.x;
    const int lane = tid & 63, wid = tid >> 6;
    const int row0 = blockIdx.y * 128, col0 = blockIdx.x * 128;
    const int wrow = (wid >> 1) * 64, wcol = (wid & 1) * 64;
    const int srow = (lane >> 2);
    const int skoff = (lane & 3) * 8;

    f32x4 acc[4][4];
    const f32x4 zr = {0.f, 0.f, 0.f, 0.f};
    #pragma unroll
    for (int m = 0; m < 4; m++)
        #pragma unroll
        for (int n = 0; n < 4; n++) acc[m][n] = zr;

    for (int k0 = 0; k0 < Kd; k0 += 32) {
        #pragma unroll
        for (int j = 0; j < 2; j++) {
            const int r = wid * 32 + j * 16;
            const ushort_t* ga = A + (size_t)(row0 + r + srow) * lda + k0 + skoff;
            __builtin_amdgcn_global_load_lds(
                (const __attribute__((address_space(1))) unsigned int*)ga,
                (__attribute__((address_space(3))) unsigned int*)(As + r * 32), 16, 0, 0);
            const ushort_t* gb = W + (size_t)(col0 + r + srow) * ldw + k0 + skoff;
            __builtin_amdgcn_global_load_lds(
                (const __attribute__((address_space(1))) unsigned int*)gb,
                (__attribute__((address_space(3))) unsigned int*)(Bs + r * 32), 16, 0, 0);
        }
        __syncthreads();
        short8 af[4], bf[4];
        #pragma unroll
        for (int m = 0; m < 4; m++)
            af[m] = *(const short8*)(As + (wrow + m * 16 + (lane & 15)) * 32 + (lane >> 4) * 8);
        #pragma unroll
        for (int n = 0; n < 4; n++)
            bf[n] = *(const short8*)(Bs + (wcol + n * 16 + (lane & 15)) * 32 + (lane >> 4) * 8);
        #pragma unroll
        for (int m = 0; m < 4; m++)
            #pragma unroll
            for (int n = 0; n < 4; n++)
                acc[m][n] = __builtin_amdgcn_mfma_f32_16x16x32_bf16(af[m], bf[n], acc[m][n], 0, 0, 0);
        __syncthreads();
    }

    #pragma unroll
    for (int n = 0; n < 4; n++) {
        const int ccol = col0 + wcol + n * 16 + (lane & 15);
        #pragma unroll
        for (int m = 0; m < 4; m++) {
            #pragma unroll
            for (int r = 0; r < 4; r++) {
                const int crow = row0 + wrow + m * 16 + (lane >> 4) * 4 + r;
                C[(size_t)crow * ldc + ccol] = acc[m][n][r];
            }
        }
    }
}

// ------------- softmax over S rows (scale 1/16), write normalized P in bf16 --------------------
// one wave per 512-length row; block = 4 rows.
__global__ __launch_bounds__(256) void softmax_k(
    const float* __restrict__ S, ushort_t* __restrict__ P)
{
    const int row = blockIdx.x * 4 + (threadIdx.x >> 6);
    const int lane = threadIdx.x & 63;
    const float* sr = S + (size_t)row * 512 + lane * 8;
    const float4 a = *(const float4*)sr;
    const float4 b = *(const float4*)(sr + 4);
    float v[8] = {a.x, a.y, a.z, a.w, b.x, b.y, b.z, b.w};
    #pragma unroll
    for (int i = 0; i < 8; i++) v[i] *= 0.0625f;
    float m = v[0];
    #pragma unroll
    for (int i = 1; i < 8; i++) m = fmaxf(m, v[i]);
    #pragma unroll
    for (int off = 32; off > 0; off >>= 1) m = fmaxf(m, __shfl_xor(m, off));
    float s = 0.f;
    #pragma unroll
    for (int i = 0; i < 8; i++) { v[i] = expf(v[i] - m); s += v[i]; }
    #pragma unroll
    for (int off = 32; off > 0; off >>= 1) s += __shfl_xor(s, off);
    const float inv = 1.f / s;
    union { ushort_t h[8]; uint4 u; } pk;
    #pragma unroll
    for (int i = 0; i < 8; i++) pk.h[i] = f2bf(v[i] * inv);
    *(uint4*)(P + (size_t)row * 512 + lane * 8) = pk.u;
}

// ------------- z-batched bf16 transpose: V[kv][d] (in qkvb v-slots) -> Vt[d][kv] ---------------
__global__ __launch_bounds__(256) void vtb_k(
    const ushort_t* __restrict__ qkvb, ushort_t* __restrict__ Vt)
{
    const int z = blockIdx.z, bl = z >> 2, hh = z & 3;
    const ushort_t* src = qkvb + (size_t)bl * 512 * 3072 + 2048 + hh * 256;
    ushort_t* dst = Vt + (size_t)z * 256 * 512;
    __shared__ ushort_t t[32][33];
    const int tx = threadIdx.x & 31, ty = threadIdx.x >> 5;
    const int gx = blockIdx.x * 32;   // d
    const int gy = blockIdx.y * 32;   // kv
    #pragma unroll
    for (int i = 0; i < 4; i++) {
        const int row = ty + i * 8;
        t[row][tx] = src[(size_t)(gy + row) * 3072 + gx + tx];
    }
    __syncthreads();
    #pragma unroll
    for (int i = 0; i < 4; i++) {
        const int nr = ty + i * 8;
        dst[(size_t)(gx + nr) * 512 + gy + tx] = t[tx][nr];
    }
}

// ------------- flat cast fp32 -> bf16 ----------------------------------------------------------
__global__ __launch_bounds__(256) void castflat_k(
    const float* __restrict__ in, ushort_t* __restrict__ outp)
{
    const size_t i4 = ((size_t)blockIdx.x * 256 + threadIdx.x) * 4;
    const float4 v = *(const float4*)(in + i4);
    union { ushort_t h[4]; uint2 u; } pk;
    pk.h[0] = f2bf(v.x); pk.h[1] = f2bf(v.y); pk.h[2] = f2bf(v.z); pk.h[3] = f2bf(v.w);
    *(uint2*)(outp + i4) = pk.u;
}

// ------------- cast fp32 (strided rows) -> packed bf16; cols is a power of two -----------------
__global__ __launch_bounds__(256) void cast_k(
    const float* __restrict__ in, int lda, ushort_t* __restrict__ outp, int logc)
{
    const size_t i4 = ((size_t)blockIdx.x * 256 + threadIdx.x) * 4;
    const size_t r = i4 >> logc;
    const int c = (int)(i4 & (((size_t)1 << logc) - 1));
    const float4 v = *(const float4*)(in + r * lda + c);
    union { ushort_t h[4]; uint2 u; } pk;
    pk.h[0] = f2bf(v.x); pk.h[1] = f2bf(v.y); pk.h[2] = f2bf(v.z); pk.h[3] = f2bf(v.w);
    *(uint2*)(outp + i4) = pk.u;
}

// ------------- transpose+cast weight: src fp32 [Kd][N] (row stride ld) -> dst bf16 [N][Kd] -----
__global__ __launch_bounds__(256) void wt_k(
    const float* __restrict__ src, int ld, int Kd, ushort_t* __restrict__ dst)
{
    __shared__ float t[32][33];
    const int tx = threadIdx.x & 31, ty = threadIdx.x >> 5;
    const int gx = blockIdx.x * 32;
    const int gy = blockIdx.y * 32;
    #pragma unroll
    for (int i = 0; i < 4; i++) {
        const int row = ty + i * 8;
        t[row][tx] = src[(size_t)(gy + row) * ld + gx + tx];
    }
    __syncthreads();
    #pragma unroll
    for (int i = 0; i < 4; i++) {
        const int nr = ty + i * 8;
        dst[(size_t)(gx + nr) * Kd + gy + tx] = f2bf(t[tx][nr]);
    }
}

// ------------- rowdot: out[row] = dot(in[row,:], w) + b ; mode1: sigmoid->shift count ----------
__global__ __launch_bounds__(256) void rowdot_k(
    const float* __restrict__ in, const float* __restrict__ w,
    const float* __restrict__ bptr, int cols, int mode,
    float* __restrict__ outf, int* __restrict__ outi)
{
    const int row = blockIdx.x, tid = threadIdx.x;
    const float* r = in + (size_t)row * cols;
    float s = 0.f;
    for (int c = tid; c < cols; c += 256) s += r[c] * w[c];
    __shared__ float red[256];
    red[tid] = s; __syncthreads();
    for (int off = 128; off > 0; off >>= 1) {
        if (tid < off) red[tid] += red[tid + off];
        __syncthreads();
    }
    if (tid == 0) {
        float y = red[0] + bptr[0];
        if (mode == 0) outf[row] = y;
        else {
            float sg = 1.f / (1.f + expf(-y));
            outi[row] = (int)(sg * (float)(Dz / 2));
        }
    }
}

// ------------- TSM shift (chunk-local: R rows) -------------------------------------------------
__global__ __launch_bounds__(256) void tsm_k(
    const float* __restrict__ x, const int* __restrict__ sn, float* __restrict__ h)
{
    size_t idx = (size_t)blockIdx.x * 256 + threadIdx.x;
    int c = (int)(idx & (Dz - 1));
    int bt = (int)(idx >> 10);
    int t = bt & (Tz - 1);
    int s = sn[bt];
    float v;
    if (c < s)            v = (t > 0)      ? x[idx - Dz] : 0.f;
    else if (c < 2 * s)   v = (t < Tz - 1) ? x[idx + Dz] : 0.f;
    else                  v = x[idx];
    h[idx] = v;
}

// ------------- h = LN(h + r), r has row-stride ldr ---------------------------------------------
__global__ __launch_bounds__(256) void addln_k(
    float* __restrict__ h, const float* __restrict__ r, int ldr,
    const float* __restrict__ g, const float* __restrict__ b)
{
    const int row = blockIdx.x, tid = threadIdx.x;
    const size_t base = (size_t)row * Dz;
    const size_t baser = (size_t)row * ldr;
    float x[4]; float s = 0.f, sq = 0.f;
    #pragma unroll
    for (int i = 0; i < 4; i++) {
        x[i] = h[base + tid + i * 256] + r[baser + tid + i * 256];
        s += x[i]; sq += x[i] * x[i];
    }
    __shared__ float rs[256], rq[256];
    rs[tid] = s; rq[tid] = sq; __syncthreads();
    for (int off = 128; off > 0; off >>= 1) {
        if (tid < off) { rs[tid] += rs[tid + off]; rq[tid] += rq[tid + off]; }
        __syncthreads();
    }
    float mean = rs[0] * (1.f / Dz);
    float var = rq[0] * (1.f / Dz) - mean * mean;
    float inv = rsqrtf(var + EPSz);
    #pragma unroll
    for (int i = 0; i < 4; i++) {
        int c = tid + i * 256;
        h[base + c] = (x[i] - mean) * inv * g[c] + b[c];
    }
}

// ------------- top-k (7 of 512) per (chunk-local) batch row ------------------------------------
__global__ __launch_bounds__(256) void topk_k(const float* __restrict__ scores, int* __restrict__ idx)
{
    const int b = blockIdx.x, tid = threadIdx.x;
    __shared__ float sv[Tz];
    __shared__ float rv[256]; __shared__ int ri[256];
    sv[tid] = scores[b * Tz + tid];
    sv[tid + 256] = scores[b * Tz + tid + 256];
    __syncthreads();
    for (int it = 0; it < TOPKz; it++) {
        float v0 = sv[tid]; int i0 = tid;
        float v1 = sv[tid + 256];
        if (v1 > v0) { v0 = v1; i0 = tid + 256; }
        rv[tid] = v0; ri[tid] = i0; __syncthreads();
        for (int off = 128; off > 0; off >>= 1) {
            if (tid < off) {
                if (rv[tid + off] > rv[tid] ||
                    (rv[tid + off] == rv[tid] && ri[tid + off] < ri[tid])) {
                    rv[tid] = rv[tid + off]; ri[tid] = ri[tid + off];
                }
            }
            __syncthreads();
        }
        if (tid == 0) { idx[b * TOPKz + it] = ri[0]; sv[ri[0]] = -INFINITY; }
        __syncthreads();
    }
}

// ------------- agg = mean of top-k rows of shared ---------------------------------------------
__global__ __launch_bounds__(256) void agg_k(
    const float* __restrict__ sh, const int* __restrict__ idx, float* __restrict__ agg)
{
    const int b = blockIdx.x, tid = threadIdx.x;
    for (int p = tid; p < Pz; p += 256) {
        float s = 0.f;
        #pragma unroll
        for (int j = 0; j < TOPKz; j++) {
            int t = idx[b * TOPKz + j];
            s += sh[((size_t)b * Tz + t) * Pz + p];
        }
        agg[b * Pz + p] = s * (1.f / TOPKz);
    }
}

// ------------- fused classifier: c1 -> logits -> softmax -> cat_emb -> cross-q -----------------
__global__ __launch_bounds__(256) void cls_k(
    const float* __restrict__ agg,
    const float* __restrict__ cc_w1, const float* __restrict__ cc_b1,
    const float* __restrict__ g2, const float* __restrict__ b2,
    const float* __restrict__ m2, const float* __restrict__ v2,
    const float* __restrict__ cc_w2, const float* __restrict__ cc_b2,
    const float* __restrict__ ce,
    const float* __restrict__ ca_wqkv, const float* __restrict__ ca_bqkv,
    float* __restrict__ logits_out, float* __restrict__ qx)
{
    const int b = blockIdx.x, tid = threadIdx.x;
    __shared__ float ag[Pz], c1s[256], sm[16], cemb[256];
    ag[tid] = agg[b * Pz + tid];
    ag[tid + 256] = agg[b * Pz + tid + 256];
    __syncthreads();
    float s = 0.f;
    for (int p = 0; p < Pz; p++) s += ag[p] * cc_w1[p * 256 + tid];
    s += cc_b1[tid];
    s = (s - m2[tid]) * rsqrtf(v2[tid] + EPSz) * g2[tid] + b2[tid];
    s = fmaxf(s, 0.f);
    c1s[tid] = s;
    __syncthreads();
    if (tid < KC) {
        float l = 0.f;
        for (int e = 0; e < 256; e++) l += c1s[e] * cc_w2[e * KC + tid];
        l += cc_b2[tid];
        sm[tid] = l;
        logits_out[b * KC + tid] = l;
    }
    __syncthreads();
    if (tid == 0) {
        float mx = sm[0];
        for (int k = 1; k < KC; k++) mx = fmaxf(mx, sm[k]);
        float su = 0.f;
        for (int k = 0; k < KC; k++) { sm[k] = expf(sm[k] - mx); su += sm[k]; }
        float inv = 1.f / su;
        for (int k = 0; k < KC; k++) sm[k] *= inv;
    }
    __syncthreads();
    float cesum = 0.f;
    #pragma unroll
    for (int k = 0; k < KC; k++) cesum += sm[k] * ce[k * 256 + tid];
    cemb[tid] = cesum; __syncthreads();
    float q = 0.f;
    for (int i = 0; i < 256; i++) q += cemb[i] * ca_wqkv[i * 768 + tid];
    qx[b * 256 + tid] = q + ca_bqkv[tid];
}

// ------------- cross-attention (Tq=1): per-batch block -----------------------------------------
__global__ __launch_bounds__(256) void xattn_k(
    const float* __restrict__ qx, const float* __restrict__ kc,
    const float* __restrict__ vc, float* __restrict__ ctx)
{
    const int b = blockIdx.x, tid = threadIdx.x;
    __shared__ float q4[256];
    __shared__ float sc[NHz][Tz];
    q4[tid] = qx[b * 256 + tid];
    __syncthreads();
    for (int si = tid; si < NHz * Tz; si += 256) {
        int hh = si >> 9, t = si & (Tz - 1);
        const float* kr = kc + ((size_t)b * Tz + t) * 256 + hh * 64;
        const float* qr = q4 + hh * 64;
        float s = 0.f;
        #pragma unroll 8
        for (int d = 0; d < 64; d++) s += qr[d] * kr[d];
        sc[hh][t] = s * 0.125f;
    }
    __syncthreads();
    const int hh = tid >> 6, lane = tid & 63;
    float mx = -INFINITY;
    for (int t = lane; t < Tz; t += 64) mx = fmaxf(mx, sc[hh][t]);
    for (int off = 32; off > 0; off >>= 1) mx = fmaxf(mx, __shfl_xor(mx, off));
    float su = 0.f;
    for (int t = lane; t < Tz; t += 64) { float e = expf(sc[hh][t] - mx); sc[hh][t] = e; su += e; }
    for (int off = 32; off > 0; off >>= 1) su += __shfl_xor(su, off);
    float inv = 1.f / su;
    __syncthreads();
    float acc = 0.f;
    for (int t = 0; t < Tz; t++) acc += sc[hh][t] * vc[((size_t)b * Tz + t) * 256 + tid];
    ctx[b * 256 + tid] = acc * inv;
}

// ------------- ctx2 = ctx @ ca_wo + ca_bo ------------------------------------------------------
__global__ __launch_bounds__(256) void ctx2_k(
    const float* __restrict__ ctx, const float* __restrict__ ca_wo,
    const float* __restrict__ ca_bo, float* __restrict__ ctx2)
{
    const int b = blockIdx.x, tid = threadIdx.x;
    __shared__ float c[256];
    c[tid] = ctx[b * 256 + tid]; __syncthreads();
    float s = 0.f;
    for (int i = 0; i < 256; i++) s += c[i] * ca_wo[i * 256 + tid];
    ctx2[b * 256 + tid] = s + ca_bo[tid];
}

// ------------- final = proj + ctx2 (broadcast over T) ------------------------------------------
__global__ __launch_bounds__(256) void addctx_k(float* __restrict__ proj, const float* __restrict__ ctx2)
{
    size_t idx = (size_t)blockIdx.x * 256 + threadIdx.x;
    int e = (int)(idx & 255);
    int b = (int)(idx >> 17);
    proj[idx] += ctx2[b * 256 + e];
}

// ==============================================================================================
extern "C" void kernel_launch(void* const* d_in, const int* in_sizes, int n_in,
                              void* d_out, int out_size, void* d_ws, size_t ws_size,
                              hipStream_t stream)
{
    const float* x       = (const float*)d_in[0];
    const float* pred_w  = (const float*)d_in[1];
    const float* pred_b  = (const float*)d_in[2];
    const float* t_wqkv  = (const float*)d_in[3];
    const float* t_bqkv  = (const float*)d_in[4];
    const float* t_wo    = (const float*)d_in[5];
    const float* t_bo    = (const float*)d_in[6];
    const float* t_ln1g  = (const float*)d_in[7];
    const float* t_ln1b  = (const float*)d_in[8];
    const float* t_w1    = (const float*)d_in[9];
    const float* t_b1    = (const float*)d_in[10];
    const float* t_w2    = (const float*)d_in[11];
    const float* t_b2    = (const float*)d_in[12];
    const float* t_ln2g  = (const float*)d_in[13];
    const float* t_ln2b  = (const float*)d_in[14];
    const float* sb_w    = (const float*)d_in[15];
    const float* sb_b    = (const float*)d_in[16];
    const float* bn1_g   = (const float*)d_in[17];
    const float* bn1_b   = (const float*)d_in[18];
    const float* bn1_m   = (const float*)d_in[19];
    const float* bn1_v   = (const float*)d_in[20];
    const float* dt_w    = (const float*)d_in[21];
    const float* dt_b    = (const float*)d_in[22];
    const float* cc_w1   = (const float*)d_in[23];
    const float* cc_b1   = (const float*)d_in[24];
    const float* bn2_g   = (const float*)d_in[25];
    const float* bn2_b   = (const float*)d_in[26];
    const float* bn2_m   = (const float*)d_in[27];
    const float* bn2_v   = (const float*)d_in[28];
    const float* cc_w2   = (const float*)d_in[29];
    const float* cc_b2   = (const float*)d_in[30];
    const float* ce      = (const float*)d_in[31];
    const float* kp_w    = (const float*)d_in[32];
    const float* kp_b    = (const float*)d_in[33];
    const float* ca_wqkv = (const float*)d_in[34];
    const float* ca_bqkv = (const float*)d_in[35];
    const float* ca_wo   = (const float*)d_in[36];
    const float* ca_bo   = (const float*)d_in[37];
    const float* fp_w    = (const float*)d_in[38];
    const float* fp_b    = (const float*)d_in[39];
    const float* df_w    = (const float*)d_in[40];
    const float* df_b    = (const float*)d_in[41];

    float* out = (float*)d_out;

    char* wp = (char*)d_ws;
    auto alloc = [&](size_t bytes) -> char* {
        char* r = wp; wp += (bytes + 255) & ~(size_t)255; return r;
    };
    int*   sn      = (int*)alloc(BT * 4);
    float* scores  = (float*)alloc(BT * 4);
    int*   tkidx   = (int*)alloc(256 * 4);
    float* aggbuf  = (float*)alloc((size_t)Bz * Pz * 4);
    float* qxbuf   = (float*)alloc((size_t)Bz * Ez * 4);
    float* ctxbuf  = (float*)alloc((size_t)Bz * Ez * 4);
    float* ctx2buf = (float*)alloc((size_t)Bz * Ez * 4);

    const size_t WT_TOTAL = 2*(size_t)3072*1024 + 2*(size_t)1024*1024 + 2*(size_t)2048*1024
                          + 2*(size_t)1024*2048 + (size_t)512*1024 + (size_t)256*512
                          + 2*(size_t)256*256 + (size_t)1024*256;
    ushort_t* wtb = (ushort_t*)alloc(WT_TOTAL * 2);
    size_t woff = 0;
    auto nxt = [&](size_t n) -> ushort_t* { ushort_t* r = wtb + woff; woff += n; return r; };
    ushort_t* qkvT[2] = { nxt((size_t)3072*1024), nxt((size_t)3072*1024) };
    ushort_t* woT[2]  = { nxt((size_t)1024*1024), nxt((size_t)1024*1024) };
    ushort_t* w1T[2]  = { nxt((size_t)2048*1024), nxt((size_t)2048*1024) };
    ushort_t* w2T[2]  = { nxt((size_t)1024*2048), nxt((size_t)1024*2048) };
    ushort_t* sbT  = nxt((size_t)512*1024);
    ushort_t* kpT  = nxt((size_t)256*512);
    ushort_t* cakT = nxt((size_t)256*256);
    ushort_t* cavT = nxt((size_t)256*256);
    ushort_t* fpT  = nxt((size_t)1024*256);

    // per-row bytes: abuf 4096 + h 4096 + qkv 12288 + qkvb 6144 + Vt 2048 + S 8192 + P 4096 = 40960
    size_t fixedB = (size_t)(wp - (char*)d_ws);
    int Bc = Bz;
    while (Bc > 1 && fixedB + (size_t)Bc * Tz * 40960 + 1048576 > ws_size) Bc >>= 1;
    const int Rmax = Bc * Tz;
    ushort_t* abuf = (ushort_t*)alloc((size_t)Rmax * 2048 * 2);
    float*    h    = (float*)alloc((size_t)Rmax * 1024 * 4);
    float*    qkv  = (float*)alloc((size_t)Rmax * 3072 * 4);
    ushort_t* qkvb = (ushort_t*)alloc((size_t)Rmax * 3072 * 2);
    ushort_t* Vt   = (ushort_t*)alloc((size_t)Bc * 4 * 256 * 512 * 2);
    float*    Sb   = (float*)alloc((size_t)Bc * 4 * 512 * 512 * 4);
    ushort_t* Pb   = (ushort_t*)alloc((size_t)Bc * 4 * 512 * 512 * 2);

    // ---- one-time weight transpose+cast ----
    for (int l = 0; l < Lz; l++) {
        wt_k<<<dim3(3072/32, 1024/32), 256, 0, stream>>>(t_wqkv + (size_t)l*1024*3072, 3072, 1024, qkvT[l]);
        wt_k<<<dim3(1024/32, 1024/32), 256, 0, stream>>>(t_wo   + (size_t)l*1024*1024, 1024, 1024, woT[l]);
        wt_k<<<dim3(2048/32, 1024/32), 256, 0, stream>>>(t_w1   + (size_t)l*1024*2048, 2048, 1024, w1T[l]);
        wt_k<<<dim3(1024/32, 2048/32), 256, 0, stream>>>(t_w2   + (size_t)l*2048*1024, 1024, 2048, w2T[l]);
    }
    wt_k<<<dim3(512/32, 1024/32), 256, 0, stream>>>(sb_w, 512, 1024, sbT);
    wt_k<<<dim3(256/32,  512/32), 256, 0, stream>>>(kp_w, 256, 512, kpT);
    wt_k<<<dim3(256/32,  256/32), 256, 0, stream>>>(ca_wqkv + Ez,     768, 256, cakT);
    wt_k<<<dim3(256/32,  256/32), 256, 0, stream>>>(ca_wqkv + 2*Ez,   768, 256, cavT);
    wt_k<<<dim3(1024/32, 256/32), 256, 0, stream>>>(fp_w, 1024, 256, fpT);

    for (int b0 = 0; b0 < Bz; b0 += Bc) {
        const int R = Bc * Tz;
        const float* xc = x + (size_t)b0 * Tz * Dz;
        int* snc = sn + (size_t)b0 * Tz;

        auto castA = [&](const float* src, int lda, int cols, int logc) {
            cast_k<<<(int)(((size_t)R * cols) / 1024), 256, 0, stream>>>(src, lda, abuf, logc);
        };
        auto MG = [&](int aldacols, const ushort_t* Wt_, const float* bias,
                      float* C, int ldc, int N, int Kd, int epi,
                      const float* g = nullptr, const float* bb = nullptr,
                      const float* m = nullptr, const float* v = nullptr) {
            mgemm_k<<<dim3(N/128, R/128), 256, 0, stream>>>(
                abuf, aldacols, Wt_, bias, C, ldc, Kd, epi, g, bb, m, v);
        };

        rowdot_k<<<R, 256, 0, stream>>>(xc, pred_w, pred_b, Dz, 1, nullptr, snc);
        tsm_k<<<(R * Dz) / 256, 256, 0, stream>>>(xc, snc, h);

        for (int l = 0; l < Lz; l++) {
            castA(h, Dz, 1024, 10);
            MG(1024, qkvT[l], t_bqkv + (size_t)l*3072, qkv, 3072, 3072, 1024, 0);
            // ---- MFMA attention: cast qkv, transpose V, S=QK^T, softmax, O=PV -> q-slots ----
            castflat_k<<<(int)(((size_t)R * 3072) / 1024), 256, 0, stream>>>(qkv, qkvb);
            vtb_k<<<dim3(8, 16, Bc * 4), 256, 0, stream>>>(qkvb, Vt);
            bgemm_k<<<dim3(4, 4, Bc * 4), 256, 0, stream>>>(
                qkvb, 3072, (size_t)512 * 3072, 256,
                qkvb + 1024, 3072, (size_t)512 * 3072, 256,
                Sb, 512, (size_t)4 * 512 * 512, 512 * 512, 256);
            softmax_k<<<R, 256, 0, stream>>>(Sb, Pb);
            bgemm_k<<<dim3(2, 4, Bc * 4), 256, 0, stream>>>(
                Pb, 512, (size_t)4 * 512 * 512, 512 * 512,
                Vt, 512, (size_t)4 * 256 * 512, 256 * 512,
                qkv, 3072, (size_t)512 * 3072, 256, 512);
            // ---- attn-out projection + residual LN + FF ----
            castA(qkv, 3072, 1024, 10);
            MG(1024, woT[l], t_bo + (size_t)l*1024, qkv + Dz, 3072, 1024, 1024, 0);
            addln_k<<<R, 256, 0, stream>>>(h, qkv + Dz, 3072,
                                           t_ln1g + (size_t)l*Dz, t_ln1b + (size_t)l*Dz);
            castA(h, Dz, 1024, 10);
            MG(1024, w1T[l], t_b1 + (size_t)l*FFz, qkv, 3072, 2048, 1024, 1);
            castA(qkv, 3072, 2048, 11);
            MG(2048, w2T[l], t_b2 + (size_t)l*Dz, qkv + FFz, 3072, 1024, 2048, 0);
            addln_k<<<R, 256, 0, stream>>>(h, qkv + FFz, 3072,
                                           t_ln2g + (size_t)l*Dz, t_ln2b + (size_t)l*Dz);
        }

        float* shared = qkv;
        float* proj   = qkv + (size_t)R * Pz;
        float* kbuf   = proj + (size_t)R * Ez;
        float* vbuf   = kbuf + (size_t)R * Ez;
        float* fin    = vbuf + (size_t)R * Ez;

        castA(h, Dz, 1024, 10);
        MG(1024, sbT, sb_b, shared, Pz, 512, 1024, 2, bn1_g, bn1_b, bn1_m, bn1_v);
        rowdot_k<<<R, 256, 0, stream>>>(shared, dt_w, dt_b, Pz, 0,
                                        scores + (size_t)b0 * Tz, nullptr);
        topk_k<<<Bc, 256, 0, stream>>>(scores + (size_t)b0 * Tz, tkidx);
        agg_k<<<Bc, 256, 0, stream>>>(shared, tkidx, aggbuf);
        cls_k<<<Bc, 256, 0, stream>>>(aggbuf, cc_w1, cc_b1, bn2_g, bn2_b, bn2_m, bn2_v,
                                      cc_w2, cc_b2, ce, ca_wqkv, ca_bqkv,
                                      out + BT + (size_t)b0 * KC, qxbuf);
        castA(shared, Pz, 512, 9);
        MG(512, kpT, kp_b, proj, Ez, 256, 512, 0);
        castA(proj, Ez, 256, 8);
        MG(256, cakT, ca_bqkv + Ez,   kbuf, Ez, 256, 256, 0);
        MG(256, cavT, ca_bqkv + 2*Ez, vbuf, Ez, 256, 256, 0);
        xattn_k<<<Bc, 256, 0, stream>>>(qxbuf, kbuf, vbuf, ctxbuf);
        ctx2_k<<<Bc, 256, 0, stream>>>(ctxbuf, ca_wo, ca_bo, ctx2buf);
        addctx_k<<<(R * Ez) / 256, 256, 0, stream>>>(proj, ctx2buf);
        castA(proj, Ez, 256, 8);
        MG(256, fpT, fp_b, h, Dz, 1024, 256, 0);
        castA(h, Dz, 1024, 10);
        MG(1024, sbT, sb_b, fin, Pz, 512, 1024, 2, bn1_g, bn1_b, bn1_m, bn1_v);
        rowdot_k<<<R, 256, 0, stream>>>(fin, df_w, df_b, Pz, 0,
                                        out + (size_t)b0 * Tz, nullptr);
    }
}

// Round 5
// 2049.136 us; speedup vs baseline: 9.8979x; 1.4814x over previous
//
#include <hip/hip_runtime.h>
#include <math.h>

#define Bz 32
#define Tz 512
#define Dz 1024
#define Pz 512
#define Ez 256
#define KC 14
#define NHz 4
#define Lz 2
#define FFz 2048
#define TOPKz 7
#define EPSz 1e-5f
#define BT (Bz*Tz)

typedef unsigned short ushort_t;
typedef __attribute__((ext_vector_type(8))) short short8;
typedef __attribute__((ext_vector_type(4))) float f32x4;

__device__ __forceinline__ ushort_t f2bf(float f) {
    union { float f; unsigned int u; } x; x.f = f;
    unsigned int r = x.u + 0x7fffu + ((x.u >> 16) & 1u);   // RNE (finite inputs)
    return (ushort_t)(r >> 16);
}

// ---------------- bf16 MFMA GEMM: C = A[M,K]bf16 @ W^T[N,K]bf16 (+bias, epi) ------------------
// Dual outputs: Cf (fp32) and/or Ch (bf16), either may be null. epi: 0=none,1=relu,2=BN+relu
__global__ __launch_bounds__(256) void mgemm_k(
    const ushort_t* __restrict__ A, int lda,
    const ushort_t* __restrict__ Wt,
    const float* __restrict__ bias,
    float* __restrict__ Cf, ushort_t* __restrict__ Ch, int ldc,
    int Kd, int epi,
    const float* __restrict__ bng, const float* __restrict__ bnb,
    const float* __restrict__ bnm, const float* __restrict__ bnv)
{
    __shared__ __align__(16) ushort_t As[128 * 32];
    __shared__ __align__(16) ushort_t Bs[128 * 32];
    const int tid = threadIdx.x;
    const int lane = tid & 63, wid = tid >> 6;
    const int row0 = blockIdx.y * 128, col0 = blockIdx.x * 128;
    const int wrow = (wid >> 1) * 64, wcol = (wid & 1) * 64;
    const int srow = (lane >> 2);
    const int skoff = (lane & 3) * 8;

    f32x4 acc[4][4];
    const f32x4 zr = {0.f, 0.f, 0.f, 0.f};
    #pragma unroll
    for (int m = 0; m < 4; m++)
        #pragma unroll
        for (int n = 0; n < 4; n++) acc[m][n] = zr;

    for (int k0 = 0; k0 < Kd; k0 += 32) {
        #pragma unroll
        for (int j = 0; j < 2; j++) {
            const int r = wid * 32 + j * 16;
            const ushort_t* ga = A + (size_t)(row0 + r + srow) * lda + k0 + skoff;
            __builtin_amdgcn_global_load_lds(
                (const __attribute__((address_space(1))) unsigned int*)ga,
                (__attribute__((address_space(3))) unsigned int*)(As + r * 32), 16, 0, 0);
            const ushort_t* gb = Wt + (size_t)(col0 + r + srow) * Kd + k0 + skoff;
            __builtin_amdgcn_global_load_lds(
                (const __attribute__((address_space(1))) unsigned int*)gb,
                (__attribute__((address_space(3))) unsigned int*)(Bs + r * 32), 16, 0, 0);
        }
        __syncthreads();
        short8 af[4], bf[4];
        #pragma unroll
        for (int m = 0; m < 4; m++)
            af[m] = *(const short8*)(As + (wrow + m * 16 + (lane & 15)) * 32 + (lane >> 4) * 8);
        #pragma unroll
        for (int n = 0; n < 4; n++)
            bf[n] = *(const short8*)(Bs + (wcol + n * 16 + (lane & 15)) * 32 + (lane >> 4) * 8);
        #pragma unroll
        for (int m = 0; m < 4; m++)
            #pragma unroll
            for (int n = 0; n < 4; n++)
                acc[m][n] = __builtin_amdgcn_mfma_f32_16x16x32_bf16(af[m], bf[n], acc[m][n], 0, 0, 0);
        __syncthreads();
    }

    #pragma unroll
    for (int n = 0; n < 4; n++) {
        const int ccol = col0 + wcol + n * 16 + (lane & 15);
        const float bb = bias[ccol];
        float bsc = 1.f, bsh = 0.f;
        if (epi == 2) {
            bsc = rsqrtf(bnv[ccol] + EPSz) * bng[ccol];
            bsh = bnb[ccol] - bnm[ccol] * bsc;
        }
        #pragma unroll
        for (int m = 0; m < 4; m++) {
            #pragma unroll
            for (int r = 0; r < 4; r++) {
                const int crow = row0 + wrow + m * 16 + (lane >> 4) * 4 + r;
                float y = acc[m][n][r] + bb;
                if (epi == 2) y = y * bsc + bsh;
                if (epi >= 1) y = fmaxf(y, 0.f);
                if (Cf) Cf[(size_t)crow * ldc + ccol] = y;
                if (Ch) Ch[(size_t)crow * ldc + ccol] = f2bf(y);
            }
        }
    }
}

// ---------------- batched bf16 MFMA GEMM over z=(batch,head): fp32 OR bf16 out -----------------
__global__ __launch_bounds__(256) void bgemm_k(
    const ushort_t* __restrict__ A0, int lda, size_t Abz, int Ahz,
    const ushort_t* __restrict__ W0, int ldw, size_t Wbz, int Whz,
    float* __restrict__ Cf0, ushort_t* __restrict__ Ch0, int ldc, size_t Cbz, int Chz, int Kd)
{
    const int z = blockIdx.z, bl = z >> 2, hh = z & 3;
    const ushort_t* A = A0 + (size_t)bl * Abz + (size_t)hh * Ahz;
    const ushort_t* W = W0 + (size_t)bl * Wbz + (size_t)hh * Whz;

    __shared__ __align__(16) ushort_t As[128 * 32];
    __shared__ __align__(16) ushort_t Bs[128 * 32];
    const int tid = threadIdx.x;
    const int lane = tid & 63, wid = tid >> 6;
    const int row0 = blockIdx.y * 128, col0 = blockIdx.x * 128;
    const int wrow = (wid >> 1) * 64, wcol = (wid & 1) * 64;
    const int srow = (lane >> 2);
    const int skoff = (lane & 3) * 8;

    f32x4 acc[4][4];
    const f32x4 zr = {0.f, 0.f, 0.f, 0.f};
    #pragma unroll
    for (int m = 0; m < 4; m++)
        #pragma unroll
        for (int n = 0; n < 4; n++) acc[m][n] = zr;

    for (int k0 = 0; k0 < Kd; k0 += 32) {
        #pragma unroll
        for (int j = 0; j < 2; j++) {
            const int r = wid * 32 + j * 16;
            const ushort_t* ga = A + (size_t)(row0 + r + srow) * lda + k0 + skoff;
            __builtin_amdgcn_global_load_lds(
                (const __attribute__((address_space(1))) unsigned int*)ga,
                (__attribute__((address_space(3))) unsigned int*)(As + r * 32), 16, 0, 0);
            const ushort_t* gb = W + (size_t)(col0 + r + srow) * ldw + k0 + skoff;
            __builtin_amdgcn_global_load_lds(
                (const __attribute__((address_space(1))) unsigned int*)gb,
                (__attribute__((address_space(3))) unsigned int*)(Bs + r * 32), 16, 0, 0);
        }
        __syncthreads();
        short8 af[4], bf[4];
        #pragma unroll
        for (int m = 0; m < 4; m++)
            af[m] = *(const short8*)(As + (wrow + m * 16 + (lane & 15)) * 32 + (lane >> 4) * 8);
        #pragma unroll
        for (int n = 0; n < 4; n++)
            bf[n] = *(const short8*)(Bs + (wcol + n * 16 + (lane & 15)) * 32 + (lane >> 4) * 8);
        #pragma unroll
        for (int m = 0; m < 4; m++)
            #pragma unroll
            for (int n = 0; n < 4; n++)
                acc[m][n] = __builtin_amdgcn_mfma_f32_16x16x32_bf16(af[m], bf[n], acc[m][n], 0, 0, 0);
        __syncthreads();
    }

    #pragma unroll
    for (int n = 0; n < 4; n++) {
        const int ccol = col0 + wcol + n * 16 + (lane & 15);
        #pragma unroll
        for (int m = 0; m < 4; m++) {
            #pragma unroll
            for (int r = 0; r < 4; r++) {
                const int crow = row0 + wrow + m * 16 + (lane >> 4) * 4 + r;
                const float y = acc[m][n][r];
                if (Cf0) (Cf0 + (size_t)bl * Cbz + (size_t)hh * Chz)[(size_t)crow * ldc + ccol] = y;
                if (Ch0) (Ch0 + (size_t)bl * Cbz + (size_t)hh * Chz)[(size_t)crow * ldc + ccol] = f2bf(y);
            }
        }
    }
}

// ------------- softmax over S rows (scale 1/16), write normalized P in bf16 --------------------
__global__ __launch_bounds__(256) void softmax_k(
    const float* __restrict__ S, ushort_t* __restrict__ P)
{
    const int row = blockIdx.x * 4 + (threadIdx.x >> 6);
    const int lane = threadIdx.x & 63;
    const float* sr = S + (size_t)row * 512 + lane * 8;
    const float4 a = *(const float4*)sr;
    const float4 b = *(const float4*)(sr + 4);
    float v[8] = {a.x, a.y, a.z, a.w, b.x, b.y, b.z, b.w};
    #pragma unroll
    for (int i = 0; i < 8; i++) v[i] *= 0.0625f;
    float m = v[0];
    #pragma unroll
    for (int i = 1; i < 8; i++) m = fmaxf(m, v[i]);
    #pragma unroll
    for (int off = 32; off > 0; off >>= 1) m = fmaxf(m, __shfl_xor(m, off));
    float s = 0.f;
    #pragma unroll
    for (int i = 0; i < 8; i++) { v[i] = expf(v[i] - m); s += v[i]; }
    #pragma unroll
    for (int off = 32; off > 0; off >>= 1) s += __shfl_xor(s, off);
    const float inv = 1.f / s;
    union { ushort_t h[8]; uint4 u; } pk;
    #pragma unroll
    for (int i = 0; i < 8; i++) pk.h[i] = f2bf(v[i] * inv);
    *(uint4*)(P + (size_t)row * 512 + lane * 8) = pk.u;
}

// ------------- z-batched bf16 transpose: V[kv][d] (qkvb v-slots) -> Vt[d][kv] ------------------
__global__ __launch_bounds__(256) void vtb_k(
    const ushort_t* __restrict__ qkvb, ushort_t* __restrict__ Vt)
{
    const int z = blockIdx.z, bl = z >> 2, hh = z & 3;
    const ushort_t* src = qkvb + (size_t)bl * 512 * 3072 + 2048 + hh * 256;
    ushort_t* dst = Vt + (size_t)z * 256 * 512;
    __shared__ ushort_t t[32][33];
    const int tx = threadIdx.x & 31, ty = threadIdx.x >> 5;
    const int gx = blockIdx.x * 32;   // d
    const int gy = blockIdx.y * 32;   // kv
    #pragma unroll
    for (int i = 0; i < 4; i++) {
        const int row = ty + i * 8;
        t[row][tx] = src[(size_t)(gy + row) * 3072 + gx + tx];
    }
    __syncthreads();
    #pragma unroll
    for (int i = 0; i < 4; i++) {
        const int nr = ty + i * 8;
        dst[(size_t)(gx + nr) * 512 + gy + tx] = t[tx][nr];
    }
}

// ------------- transpose+cast weight: src fp32 [Kd][N] (row stride ld) -> dst bf16 [N][Kd] -----
__global__ __launch_bounds__(256) void wt_k(
    const float* __restrict__ src, int ld, int Kd, ushort_t* __restrict__ dst)
{
    __shared__ float t[32][33];
    const int tx = threadIdx.x & 31, ty = threadIdx.x >> 5;
    const int gx = blockIdx.x * 32;
    const int gy = blockIdx.y * 32;
    #pragma unroll
    for (int i = 0; i < 4; i++) {
        const int row = ty + i * 8;
        t[row][tx] = src[(size_t)(gy + row) * ld + gx + tx];
    }
    __syncthreads();
    #pragma unroll
    for (int i = 0; i < 4; i++) {
        const int nr = ty + i * 8;
        dst[(size_t)(gx + nr) * Kd + gy + tx] = f2bf(t[tx][nr]);
    }
}

// ------------- fused shift-predictor + TSM shift (dual fp32/bf16 out) --------------------------
__global__ __launch_bounds__(256) void predshift_k(
    const float* __restrict__ x, const float* __restrict__ pred_w,
    const float* __restrict__ pred_b, float* __restrict__ h, ushort_t* __restrict__ hb)
{
    const int row = blockIdx.x, tid = threadIdx.x;
    const size_t base = (size_t)row * Dz;
    float s = 0.f;
    #pragma unroll
    for (int i = 0; i < 4; i++) {
        int c = tid + i * 256;
        s += x[base + c] * pred_w[c];
    }
    __shared__ float red[256];
    __shared__ int sns;
    red[tid] = s; __syncthreads();
    for (int off = 128; off > 0; off >>= 1) {
        if (tid < off) red[tid] += red[tid + off];
        __syncthreads();
    }
    if (tid == 0) {
        float sg = 1.f / (1.f + expf(-(red[0] + pred_b[0])));
        sns = (int)(sg * (float)(Dz / 2));
    }
    __syncthreads();
    const int sn = sns;
    const int t = row & (Tz - 1);
    #pragma unroll
    for (int i = 0; i < 4; i++) {
        const int c = tid + i * 256;
        const size_t idx = base + c;
        float v;
        if (c < sn)          v = (t > 0)      ? x[idx - Dz] : 0.f;
        else if (c < 2 * sn) v = (t < Tz - 1) ? x[idx + Dz] : 0.f;
        else                 v = x[idx];
        h[idx] = v; hb[idx] = f2bf(v);
    }
}

// ------------- h = LN(h + r); dual write h fp32 + hb bf16 --------------------------------------
__global__ __launch_bounds__(256) void addln_k(
    float* __restrict__ h, ushort_t* __restrict__ hb,
    const float* __restrict__ r, int ldr,
    const float* __restrict__ g, const float* __restrict__ b)
{
    const int row = blockIdx.x, tid = threadIdx.x;
    const size_t base = (size_t)row * Dz;
    const size_t baser = (size_t)row * ldr;
    float x[4]; float s = 0.f, sq = 0.f;
    #pragma unroll
    for (int i = 0; i < 4; i++) {
        x[i] = h[base + tid + i * 256] + r[baser + tid + i * 256];
        s += x[i]; sq += x[i] * x[i];
    }
    __shared__ float rs[256], rq[256];
    rs[tid] = s; rq[tid] = sq; __syncthreads();
    for (int off = 128; off > 0; off >>= 1) {
        if (tid < off) { rs[tid] += rs[tid + off]; rq[tid] += rq[tid + off]; }
        __syncthreads();
    }
    float mean = rs[0] * (1.f / Dz);
    float var = rq[0] * (1.f / Dz) - mean * mean;
    float inv = rsqrtf(var + EPSz);
    #pragma unroll
    for (int i = 0; i < 4; i++) {
        int c = tid + i * 256;
        float y = (x[i] - mean) * inv * g[c] + b[c];
        h[base + c] = y; hb[base + c] = f2bf(y);
    }
}

// ------------- rowdot: out[row] = dot(in[row,:512], w) + b -------------------------------------
__global__ __launch_bounds__(256) void rowdot_k(
    const float* __restrict__ in, const float* __restrict__ w,
    const float* __restrict__ bptr, float* __restrict__ outf)
{
    const int row = blockIdx.x, tid = threadIdx.x;
    const float* r = in + (size_t)row * Pz;
    float s = 0.f;
    #pragma unroll
    for (int c = tid; c < Pz; c += 256) s += r[c] * w[c];
    __shared__ float red[256];
    red[tid] = s; __syncthreads();
    for (int off = 128; off > 0; off >>= 1) {
        if (tid < off) red[tid] += red[tid + off];
        __syncthreads();
    }
    if (tid == 0) outf[row] = red[0] + bptr[0];
}

// ------------- top-k (7 of 512) per (chunk-local) batch row ------------------------------------
__global__ __launch_bounds__(256) void topk_k(const float* __restrict__ scores, int* __restrict__ idx)
{
    const int b = blockIdx.x, tid = threadIdx.x;
    __shared__ float sv[Tz];
    __shared__ float rv[256]; __shared__ int ri[256];
    sv[tid] = scores[b * Tz + tid];
    sv[tid + 256] = scores[b * Tz + tid + 256];
    __syncthreads();
    for (int it = 0; it < TOPKz; it++) {
        float v0 = sv[tid]; int i0 = tid;
        float v1 = sv[tid + 256];
        if (v1 > v0) { v0 = v1; i0 = tid + 256; }
        rv[tid] = v0; ri[tid] = i0; __syncthreads();
        for (int off = 128; off > 0; off >>= 1) {
            if (tid < off) {
                if (rv[tid + off] > rv[tid] ||
                    (rv[tid + off] == rv[tid] && ri[tid + off] < ri[tid])) {
                    rv[tid] = rv[tid + off]; ri[tid] = ri[tid + off];
                }
            }
            __syncthreads();
        }
        if (tid == 0) { idx[b * TOPKz + it] = ri[0]; sv[ri[0]] = -INFINITY; }
        __syncthreads();
    }
}

// ------------- agg = mean of top-k rows of shared ---------------------------------------------
__global__ __launch_bounds__(256) void agg_k(
    const float* __restrict__ sh, const int* __restrict__ idx, float* __restrict__ agg)
{
    const int b = blockIdx.x, tid = threadIdx.x;
    for (int p = tid; p < Pz; p += 256) {
        float s = 0.f;
        #pragma unroll
        for (int j = 0; j < TOPKz; j++) {
            int t = idx[b * TOPKz + j];
            s += sh[((size_t)b * Tz + t) * Pz + p];
        }
        agg[b * Pz + p] = s * (1.f / TOPKz);
    }
}

// ------------- fused classifier: c1 -> logits -> softmax -> cat_emb -> cross-q -----------------
__global__ __launch_bounds__(256) void cls_k(
    const float* __restrict__ agg,
    const float* __restrict__ cc_w1, const float* __restrict__ cc_b1,
    const float* __restrict__ g2, const float* __restrict__ b2,
    const float* __restrict__ m2, const float* __restrict__ v2,
    const float* __restrict__ cc_w2, const float* __restrict__ cc_b2,
    const float* __restrict__ ce,
    const float* __restrict__ ca_wqkv, const float* __restrict__ ca_bqkv,
    float* __restrict__ logits_out, float* __restrict__ qx)
{
    const int b = blockIdx.x, tid = threadIdx.x;
    __shared__ float ag[Pz], c1s[256], sm[16], cemb[256];
    ag[tid] = agg[b * Pz + tid];
    ag[tid + 256] = agg[b * Pz + tid + 256];
    __syncthreads();
    float s = 0.f;
    for (int p = 0; p < Pz; p++) s += ag[p] * cc_w1[p * 256 + tid];
    s += cc_b1[tid];
    s = (s - m2[tid]) * rsqrtf(v2[tid] + EPSz) * g2[tid] + b2[tid];
    s = fmaxf(s, 0.f);
    c1s[tid] = s;
    __syncthreads();
    if (tid < KC) {
        float l = 0.f;
        for (int e = 0; e < 256; e++) l += c1s[e] * cc_w2[e * KC + tid];
        l += cc_b2[tid];
        sm[tid] = l;
        logits_out[b * KC + tid] = l;
    }
    __syncthreads();
    if (tid == 0) {
        float mx = sm[0];
        for (int k = 1; k < KC; k++) mx = fmaxf(mx, sm[k]);
        float su = 0.f;
        for (int k = 0; k < KC; k++) { sm[k] = expf(sm[k] - mx); su += sm[k]; }
        float inv = 1.f / su;
        for (int k = 0; k < KC; k++) sm[k] *= inv;
    }
    __syncthreads();
    float cesum = 0.f;
    #pragma unroll
    for (int k = 0; k < KC; k++) cesum += sm[k] * ce[k * 256 + tid];
    cemb[tid] = cesum; __syncthreads();
    float q = 0.f;
    for (int i = 0; i < 256; i++) q += cemb[i] * ca_wqkv[i * 768 + tid];
    qx[b * 256 + tid] = q + ca_bqkv[tid];
}

// ------------- cross-attention (Tq=1) on combined kv[R,512] ------------------------------------
__global__ __launch_bounds__(256) void xattn_k(
    const float* __restrict__ qx, const float* __restrict__ kv, float* __restrict__ ctx)
{
    const int b = blockIdx.x, tid = threadIdx.x;
    __shared__ float q4[256];
    __shared__ float sc[NHz][Tz];
    q4[tid] = qx[b * 256 + tid];
    __syncthreads();
    for (int si = tid; si < NHz * Tz; si += 256) {
        int hh = si >> 9, t = si & (Tz - 1);
        const float* kr = kv + ((size_t)b * Tz + t) * 512 + hh * 64;
        const float* qr = q4 + hh * 64;
        float s = 0.f;
        #pragma unroll 8
        for (int d = 0; d < 64; d++) s += qr[d] * kr[d];
        sc[hh][t] = s * 0.125f;
    }
    __syncthreads();
    const int hh = tid >> 6, lane = tid & 63;
    float mx = -INFINITY;
    for (int t = lane; t < Tz; t += 64) mx = fmaxf(mx, sc[hh][t]);
    for (int off = 32; off > 0; off >>= 1) mx = fmaxf(mx, __shfl_xor(mx, off));
    float su = 0.f;
    for (int t = lane; t < Tz; t += 64) { float e = expf(sc[hh][t] - mx); sc[hh][t] = e; su += e; }
    for (int off = 32; off > 0; off >>= 1) su += __shfl_xor(su, off);
    float inv = 1.f / su;
    __syncthreads();
    float acc = 0.f;
    for (int t = 0; t < Tz; t++) acc += sc[hh][t] * kv[((size_t)b * Tz + t) * 512 + 256 + tid];
    ctx[b * 256 + tid] = acc * inv;
}

// ------------- ctx2 = ctx @ ca_wo + ca_bo ------------------------------------------------------
__global__ __launch_bounds__(256) void ctx2_k(
    const float* __restrict__ ctx, const float* __restrict__ ca_wo,
    const float* __restrict__ ca_bo, float* __restrict__ ctx2)
{
    const int b = blockIdx.x, tid = threadIdx.x;
    __shared__ float c[256];
    c[tid] = ctx[b * 256 + tid]; __syncthreads();
    float s = 0.f;
    for (int i = 0; i < 256; i++) s += c[i] * ca_wo[i * 256 + tid];
    ctx2[b * 256 + tid] = s + ca_bo[tid];
}

// ------------- fb = bf16(proj + ctx2) (broadcast over T) ---------------------------------------
__global__ __launch_bounds__(256) void addctx_k(
    const float* __restrict__ proj, const float* __restrict__ ctx2, ushort_t* __restrict__ fb)
{
    size_t idx = (size_t)blockIdx.x * 256 + threadIdx.x;   // over R*E
    int e = (int)(idx & 255);
    int b = (int)(idx >> 17);                              // T*E = 2^17
    fb[idx] = f2bf(proj[idx] + ctx2[b * 256 + e]);
}

// ==============================================================================================
extern "C" void kernel_launch(void* const* d_in, const int* in_sizes, int n_in,
                              void* d_out, int out_size, void* d_ws, size_t ws_size,
                              hipStream_t stream)
{
    const float* x       = (const float*)d_in[0];
    const float* pred_w  = (const float*)d_in[1];
    const float* pred_b  = (const float*)d_in[2];
    const float* t_wqkv  = (const float*)d_in[3];
    const float* t_bqkv  = (const float*)d_in[4];
    const float* t_wo    = (const float*)d_in[5];
    const float* t_bo    = (const float*)d_in[6];
    const float* t_ln1g  = (const float*)d_in[7];
    const float* t_ln1b  = (const float*)d_in[8];
    const float* t_w1    = (const float*)d_in[9];
    const float* t_b1    = (const float*)d_in[10];
    const float* t_w2    = (const float*)d_in[11];
    const float* t_b2    = (const float*)d_in[12];
    const float* t_ln2g  = (const float*)d_in[13];
    const float* t_ln2b  = (const float*)d_in[14];
    const float* sb_w    = (const float*)d_in[15];
    const float* sb_b    = (const float*)d_in[16];
    const float* bn1_g   = (const float*)d_in[17];
    const float* bn1_b   = (const float*)d_in[18];
    const float* bn1_m   = (const float*)d_in[19];
    const float* bn1_v   = (const float*)d_in[20];
    const float* dt_w    = (const float*)d_in[21];
    const float* dt_b    = (const float*)d_in[22];
    const float* cc_w1   = (const float*)d_in[23];
    const float* cc_b1   = (const float*)d_in[24];
    const float* bn2_g   = (const float*)d_in[25];
    const float* bn2_b   = (const float*)d_in[26];
    const float* bn2_m   = (const float*)d_in[27];
    const float* bn2_v   = (const float*)d_in[28];
    const float* cc_w2   = (const float*)d_in[29];
    const float* cc_b2   = (const float*)d_in[30];
    const float* ce      = (const float*)d_in[31];
    const float* kp_w    = (const float*)d_in[32];
    const float* kp_b    = (const float*)d_in[33];
    const float* ca_wqkv = (const float*)d_in[34];
    const float* ca_bqkv = (const float*)d_in[35];
    const float* ca_wo   = (const float*)d_in[36];
    const float* ca_bo   = (const float*)d_in[37];
    const float* fp_w    = (const float*)d_in[38];
    const float* fp_b    = (const float*)d_in[39];
    const float* df_w    = (const float*)d_in[40];
    const float* df_b    = (const float*)d_in[41];

    float* out = (float*)d_out;

    char* wp = (char*)d_ws;
    auto alloc = [&](size_t bytes) -> char* {
        char* r = wp; wp += (bytes + 255) & ~(size_t)255; return r;
    };
    float* scores  = (float*)alloc(BT * 4);
    int*   tkidx   = (int*)alloc(256 * 4);
    float* aggbuf  = (float*)alloc((size_t)Bz * Pz * 4);
    float* qxbuf   = (float*)alloc((size_t)Bz * Ez * 4);
    float* ctxbuf  = (float*)alloc((size_t)Bz * Ez * 4);
    float* ctx2buf = (float*)alloc((size_t)Bz * Ez * 4);

    const size_t WT_TOTAL = 2*(size_t)3072*1024 + 2*(size_t)1024*1024 + 2*(size_t)2048*1024
                          + 2*(size_t)1024*2048 + (size_t)512*1024 + (size_t)256*512
                          + 2*(size_t)256*256 + (size_t)1024*256;
    ushort_t* wtb = (ushort_t*)alloc(WT_TOTAL * 2);
    size_t woff = 0;
    auto nxt = [&](size_t n) -> ushort_t* { ushort_t* r = wtb + woff; woff += n; return r; };
    ushort_t* qkvT[2] = { nxt((size_t)3072*1024), nxt((size_t)3072*1024) };
    ushort_t* woT[2]  = { nxt((size_t)1024*1024), nxt((size_t)1024*1024) };
    ushort_t* w1T[2]  = { nxt((size_t)2048*1024), nxt((size_t)2048*1024) };
    ushort_t* w2T[2]  = { nxt((size_t)1024*2048), nxt((size_t)1024*2048) };
    ushort_t* sbT  = nxt((size_t)512*1024);
    ushort_t* kpT  = nxt((size_t)256*512);
    ushort_t* kvT  = nxt((size_t)512*256);   // combined cross k|v weight [512][256]
    ushort_t* fpT  = nxt((size_t)1024*256);

    // per-row bytes: h 4096 + hb 2048 + qkvb 6144 + scr 8192 + Pb 4096 + Vt 2048 = 26624
    size_t fixedB = (size_t)(wp - (char*)d_ws);
    int Bc = Bz;
    while (Bc > 1 && fixedB + (size_t)Bc * Tz * 26624 + 1048576 > ws_size) Bc >>= 1;
    const int Rmax = Bc * Tz;
    float*    h    = (float*)alloc((size_t)Rmax * 1024 * 4);
    ushort_t* hb   = (ushort_t*)alloc((size_t)Rmax * 1024 * 2);
    ushort_t* qkvb = (ushort_t*)alloc((size_t)Rmax * 3072 * 2);
    float*    scr  = (float*)alloc((size_t)Rmax * 2048 * 4);   // S / wo-out / ff2-out / tail f32
    ushort_t* Pb   = (ushort_t*)alloc((size_t)Rmax * 2048 * 2);
    ushort_t* Vt   = (ushort_t*)alloc((size_t)Rmax * 1024 * 2);

    // ---- one-time weight transpose+cast ----
    for (int l = 0; l < Lz; l++) {
        wt_k<<<dim3(3072/32, 1024/32), 256, 0, stream>>>(t_wqkv + (size_t)l*1024*3072, 3072, 1024, qkvT[l]);
        wt_k<<<dim3(1024/32, 1024/32), 256, 0, stream>>>(t_wo   + (size_t)l*1024*1024, 1024, 1024, woT[l]);
        wt_k<<<dim3(2048/32, 1024/32), 256, 0, stream>>>(t_w1   + (size_t)l*1024*2048, 2048, 1024, w1T[l]);
        wt_k<<<dim3(1024/32, 2048/32), 256, 0, stream>>>(t_w2   + (size_t)l*2048*1024, 1024, 2048, w2T[l]);
    }
    wt_k<<<dim3(512/32, 1024/32), 256, 0, stream>>>(sb_w, 512, 1024, sbT);
    wt_k<<<dim3(256/32,  512/32), 256, 0, stream>>>(kp_w, 256, 512, kpT);
    wt_k<<<dim3(256/32,  256/32), 256, 0, stream>>>(ca_wqkv + Ez,     768, 256, kvT);
    wt_k<<<dim3(256/32,  256/32), 256, 0, stream>>>(ca_wqkv + 2*Ez,   768, 256, kvT + (size_t)256*256);
    wt_k<<<dim3(1024/32, 256/32), 256, 0, stream>>>(fp_w, 1024, 256, fpT);

    for (int b0 = 0; b0 < Bz; b0 += Bc) {
        const int R = Bc * Tz;
        const float* xc = x + (size_t)b0 * Tz * Dz;

        auto MG = [&](const ushort_t* Ain, int lda, const ushort_t* Wt_, const float* bias,
                      float* Cf, ushort_t* Ch, int ldc, int N, int Kd, int epi,
                      const float* g = nullptr, const float* bb = nullptr,
                      const float* m = nullptr, const float* v = nullptr) {
            mgemm_k<<<dim3(N/128, R/128), 256, 0, stream>>>(
                Ain, lda, Wt_, bias, Cf, Ch, ldc, Kd, epi, g, bb, m, v);
        };

        // 1. fused shift-predictor + TSM -> h, hb
        predshift_k<<<R, 256, 0, stream>>>(xc, pred_w, pred_b, h, hb);

        // 2. transformer layers
        for (int l = 0; l < Lz; l++) {
            MG(hb, 1024, qkvT[l], t_bqkv + (size_t)l*3072, nullptr, qkvb, 3072, 3072, 1024, 0);
            vtb_k<<<dim3(8, 16, Bc * 4), 256, 0, stream>>>(qkvb, Vt);
            bgemm_k<<<dim3(4, 4, Bc * 4), 256, 0, stream>>>(
                qkvb, 3072, (size_t)512 * 3072, 256,
                qkvb + 1024, 3072, (size_t)512 * 3072, 256,
                scr, nullptr, 512, (size_t)4 * 512 * 512, 512 * 512, 256);
            softmax_k<<<R, 256, 0, stream>>>(scr, Pb);
            bgemm_k<<<dim3(2, 4, Bc * 4), 256, 0, stream>>>(
                Pb, 512, (size_t)4 * 512 * 512, 512 * 512,
                Vt, 512, (size_t)4 * 256 * 512, 256 * 512,
                nullptr, qkvb, 3072, (size_t)512 * 3072, 256, 512);
            MG(qkvb, 3072, woT[l], t_bo + (size_t)l*1024, scr, nullptr, 1024, 1024, 1024, 0);
            addln_k<<<R, 256, 0, stream>>>(h, hb, scr, 1024,
                                           t_ln1g + (size_t)l*Dz, t_ln1b + (size_t)l*Dz);
            MG(hb, 1024, w1T[l], t_b1 + (size_t)l*FFz, nullptr, qkvb, 2048, 2048, 1024, 1);
            MG(qkvb, 2048, w2T[l], t_b2 + (size_t)l*Dz, scr, nullptr, 1024, 1024, 2048, 0);
            addln_k<<<R, 256, 0, stream>>>(h, hb, scr, 1024,
                                           t_ln2g + (size_t)l*Dz, t_ln2b + (size_t)l*Dz);
        }

        // tail buffers sublet scr (f32) and Pb (bf16)
        float*    shared  = scr;                       // [R,512]
        float*    proj    = scr + (size_t)R * 512;     // [R,256]
        float*    kvb     = scr + (size_t)R * 768;     // [R,512] combined k|v
        float*    fin     = scr + (size_t)R * 1280;    // [R,512]
        ushort_t* sharedb = Pb;                        // [R,512]
        ushort_t* projb   = Pb + (size_t)R * 512;      // [R,256]
        ushort_t* fb      = Pb + (size_t)R * 768;      // [R,256]
        ushort_t* fpb     = qkvb;                      // [R,1024]

        // 3. shared = relu(BN1(h @ sb_w + sb_b))  (dual out)
        MG(hb, 1024, sbT, sb_b, shared, sharedb, 512, 512, 1024, 2, bn1_g, bn1_b, bn1_m, bn1_v);
        // 4. scores, top-k, agg, classifier
        rowdot_k<<<R, 256, 0, stream>>>(shared, dt_w, dt_b, scores + (size_t)b0 * Tz);
        topk_k<<<Bc, 256, 0, stream>>>(scores + (size_t)b0 * Tz, tkidx);
        agg_k<<<Bc, 256, 0, stream>>>(shared, tkidx, aggbuf);
        cls_k<<<Bc, 256, 0, stream>>>(aggbuf, cc_w1, cc_b1, bn2_g, bn2_b, bn2_m, bn2_v,
                                      cc_w2, cc_b2, ce, ca_wqkv, ca_bqkv,
                                      out + BT + (size_t)b0 * KC, qxbuf);
        // 5. proj (dual), combined cross k|v
        MG(sharedb, 512, kpT, kp_b, proj, projb, 256, 256, 512, 0);
        {
            // combined bias for k|v: ca_bqkv[E..3E) is contiguous
            MG(projb, 256, kvT, ca_bqkv + Ez, kvb, nullptr, 512, 512, 256, 0);
        }
        // 6. cross attention + final fuse
        xattn_k<<<Bc, 256, 0, stream>>>(qxbuf, kvb, ctxbuf);
        ctx2_k<<<Bc, 256, 0, stream>>>(ctxbuf, ca_wo, ca_bo, ctx2buf);
        addctx_k<<<(R * Ez) / 256, 256, 0, stream>>>(proj, ctx2buf, fb);
        // 7. fp_out (bf16) -> fin (BN+relu fp32) -> seg
        MG(fb, 256, fpT, fp_b, nullptr, fpb, 1024, 1024, 256, 0);
        MG(fpb, 1024, sbT, sb_b, fin, nullptr, 512, 512, 1024, 2, bn1_g, bn1_b, bn1_m, bn1_v);
        rowdot_k<<<R, 256, 0, stream>>>(fin, df_w, df_b, out + (size_t)b0 * Tz);
    }
}